// Round 7
// baseline (4489.089 us; speedup 1.0000x reference)
//
#include <hip/hip_runtime.h>
#include <hip/hip_bf16.h>
#include <cstdint>
#include <cstddef>

// Problem constants (fixed by setup_inputs in the reference)
#define Bc   1024
#define NIFc 2048
#define Vc   10000
#define Ec   512
#define Hc   1024
#define Lc   32
#define NDc  3
#define G4c  4096   // 4*H
#define NTv  79     // ceil(V/128) logits tiles
#define TMLD 80     // tilemax row stride
#define XLD  3584   // h3x row stride: [x_hi(512) | h_hi|h_lo|h_hi(3072)]
#define XOFF 512
#define RLD  1536   // xh_r row stride: [x(512) | h(1024)]

typedef __attribute__((ext_vector_type(4))) float f32x4;
typedef __attribute__((ext_vector_type(8))) short s16x8;
typedef __attribute__((ext_vector_type(4))) short s16x4;

// Receiver gate-row permutation: orig gate-row n = g*1024+u  <->  permuted
// p = (u>>4)*64 + g*16 + (u&15).  A 128-wide MFMA tile then holds 32 complete
// (i,f,g,o) quadruples -> LSTM cell can be applied in the GEMM epilogue.
__device__ __host__ __forceinline__ int rperm_orig(int p) {
    return ((p >> 4) & 3) * Hc + (p >> 6) * 16 + (p & 15);
}

// ===========================================================================
// bf16 MFMA GEMM body (128x128 tile, BK=64, 4 waves, gld_lds w=16, swizzle)
// GemmSmem is EXACTLY 32 KiB -> 5 blocks/CU (vs 4 at 33 KB): the per-step
// fused dispatches (1144 / 1280 blocks) become fully co-resident.
// The tile_max scratch and argmax scratch alias As (dead after the K-loop;
// all aliased stores are behind a __syncthreads()).
// ===========================================================================
#define GBM 128
#define GBN 128
#define GBK 64

struct __align__(16) GemmSmem {
    __hip_bfloat16 As[GBM * GBK];
    __hip_bfloat16 Ws[GBN * GBK];
};

__device__ __forceinline__ void gld_lds16(void* lds, const void* g) {
    __builtin_amdgcn_global_load_lds(
        (const __attribute__((address_space(1))) unsigned int*)g,
        (__attribute__((address_space(3))) unsigned int*)lds,
        16, 0, 0);
}

template<int OBF>
__device__ __forceinline__ void gemm_body(
    GemmSmem& sm,
    const __hip_bfloat16* __restrict__ A, int lda,
    const __hip_bfloat16* __restrict__ W, int ldw,
    const float* __restrict__ bias, void* __restrict__ Cv,
    int M, int N, int K, int bx, int by,
    float* __restrict__ tile_max, int tmld)
{
    __hip_bfloat16* As = sm.As;
    __hip_bfloat16* Ws = sm.Ws;

    const int tid  = threadIdx.x;
    const int lane = tid & 63;
    const int wave = tid >> 6;
    const int m0 = by * GBM;
    const int n0 = bx * GBN;

    const __hip_bfloat16* ag[4];
    const __hip_bfloat16* wg[4];
    #pragma unroll
    for (int r = 0; r < 4; ++r) {
        int p = r * 256 + tid;
        int m = p >> 3;
        int q = (p & 7) ^ (m & 7);
        int am = m0 + m; if (am >= M) am = M - 1;
        ag[r] = A + (size_t)am * lda + q * 8;
        int wn = n0 + m; if (wn >= N) wn = N - 1;
        wg[r] = W + (size_t)wn * ldw + q * 8;
    }

    f32x4 acc[4][4];
    #pragma unroll
    for (int i = 0; i < 4; ++i)
        #pragma unroll
        for (int j = 0; j < 4; ++j)
            acc[i][j] = (f32x4)(0.0f);

    const int hm = (wave & 1) << 6;
    const int hn = (wave >> 1) << 6;
    const int lm = lane & 15;
    const int quad = lane >> 4;

    const int nk = K >> 6;
    for (int kt = 0; kt < nk; ++kt) {
        __syncthreads();
        #pragma unroll
        for (int r = 0; r < 4; ++r) {
            int ldsbase = (r * 256 + wave * 64) * 8;
            gld_lds16(As + ldsbase, ag[r]);
            gld_lds16(Ws + ldsbase, wg[r]);
            ag[r] += GBK;
            wg[r] += GBK;
        }
        __syncthreads();
        #pragma unroll
        for (int c = 0; c < 2; ++c) {
            s16x8 af[4], wf[4];
            int q = c * 4 + quad;
            #pragma unroll
            for (int i = 0; i < 4; ++i) {
                int m = hm + i * 16 + lm;
                af[i] = *(const s16x8*)(As + ((m << 3) + (q ^ (m & 7))) * 8);
                int n = hn + i * 16 + lm;
                wf[i] = *(const s16x8*)(Ws + ((n << 3) + (q ^ (n & 7))) * 8);
            }
            #pragma unroll
            for (int i = 0; i < 4; ++i)
                #pragma unroll
                for (int j = 0; j < 4; ++j)
                    acc[i][j] = __builtin_amdgcn_mfma_f32_16x16x32_bf16(
                        af[i], wf[j], acc[i][j], 0, 0, 0);
        }
    }

    // epilogue: C/D layout col=lane&15, row=quad*4+reg
    float rowmax[4][4];
    #pragma unroll
    for (int i = 0; i < 4; ++i)
        #pragma unroll
        for (int rr = 0; rr < 4; ++rr)
            rowmax[i][rr] = -__builtin_inff();

    #pragma unroll
    for (int i = 0; i < 4; ++i) {
        int mbase = m0 + hm + i * 16 + quad * 4;
        #pragma unroll
        for (int j = 0; j < 4; ++j) {
            int n = n0 + hn + j * 16 + lm;
            if (n < N) {
                float bv = bias ? bias[n] : 0.0f;
                #pragma unroll
                for (int rr = 0; rr < 4; ++rr) {
                    float v = acc[i][j][rr] + bv;
                    float vs = v;
                    if (OBF) {
                        __hip_bfloat16 vb = __float2bfloat16(v);
                        vs = __bfloat162float(vb);
                        if (mbase + rr < M)
                            ((__hip_bfloat16*)Cv)[(size_t)(mbase + rr) * N + n] = vb;
                    } else {
                        if (mbase + rr < M)
                            ((float*)Cv)[(size_t)(mbase + rr) * N + n] = v;
                    }
                    rowmax[i][rr] = fmaxf(rowmax[i][rr], vs);
                }
            }
        }
    }

    if (tile_max) {
        float* smax = (float*)sm.As;   // alias: As dead; stores are post-barrier
        #pragma unroll
        for (int i = 0; i < 4; ++i)
            #pragma unroll
            for (int rr = 0; rr < 4; ++rr) {
                float v = rowmax[i][rr];
                v = fmaxf(v, __shfl_xor(v, 1));
                v = fmaxf(v, __shfl_xor(v, 2));
                v = fmaxf(v, __shfl_xor(v, 4));
                v = fmaxf(v, __shfl_xor(v, 8));
                rowmax[i][rr] = v;
            }
        __syncthreads();
        if (hn == 0 && lm == 0) {
            #pragma unroll
            for (int i = 0; i < 4; ++i)
                #pragma unroll
                for (int rr = 0; rr < 4; ++rr)
                    smax[hm + i * 16 + quad * 4 + rr] = rowmax[i][rr];
        }
        __syncthreads();
        if (hn == 64 && lm == 0) {
            #pragma unroll
            for (int i = 0; i < 4; ++i)
                #pragma unroll
                for (int rr = 0; rr < 4; ++rr) {
                    int r = hm + i * 16 + quad * 4 + rr;
                    smax[r] = fmaxf(smax[r], rowmax[i][rr]);
                }
        }
        __syncthreads();
        if (tid < GBM)
            tile_max[(size_t)(m0 + tid) * tmld + bx] = smax[tid];
    }
}

// ---------------------------------------------------------------------------
// Receiver GEMM + fused LSTM cell (one-step-delayed recurrence).
// ---------------------------------------------------------------------------
__device__ __forceinline__ void recv_gemm_cell_body(
    GemmSmem& sm,
    const __hip_bfloat16* __restrict__ A,
    const __hip_bfloat16* __restrict__ W,
    const float* __restrict__ biasp,
    const __hip_bfloat16* __restrict__ Xg,
    const int* __restrict__ tok,
    float* __restrict__ cr,
    __hip_bfloat16* __restrict__ xh_out,
    int bx, int by)
{
    __hip_bfloat16* As = sm.As;
    __hip_bfloat16* Ws = sm.Ws;

    const int tid  = threadIdx.x;
    const int lane = tid & 63;
    const int wave = tid >> 6;
    const int m0 = by * GBM;
    const int n0 = bx * GBN;

    const __hip_bfloat16* ag[4];
    const __hip_bfloat16* wg[4];
    #pragma unroll
    for (int r = 0; r < 4; ++r) {
        int p = r * 256 + tid;
        int m = p >> 3;
        int q = (p & 7) ^ (m & 7);
        ag[r] = A + (size_t)(m0 + m) * RLD + q * 8;
        wg[r] = W + (size_t)(n0 + m) * RLD + q * 8;
    }

    f32x4 acc[4][4];
    #pragma unroll
    for (int i = 0; i < 4; ++i)
        #pragma unroll
        for (int j = 0; j < 4; ++j)
            acc[i][j] = (f32x4)(0.0f);

    const int hm = (wave & 1) << 6;
    const int hn = (wave >> 1) << 6;
    const int lm = lane & 15;
    const int quad = lane >> 4;

    for (int kt = 0; kt < Hc / GBK; ++kt) {
        __syncthreads();
        #pragma unroll
        for (int r = 0; r < 4; ++r) {
            int ldsbase = (r * 256 + wave * 64) * 8;
            gld_lds16(As + ldsbase, ag[r]);
            gld_lds16(Ws + ldsbase, wg[r]);
            ag[r] += GBK;
            wg[r] += GBK;
        }
        __syncthreads();
        #pragma unroll
        for (int c = 0; c < 2; ++c) {
            s16x8 af[4], wf[4];
            int q = c * 4 + quad;
            #pragma unroll
            for (int i = 0; i < 4; ++i) {
                int m = hm + i * 16 + lm;
                af[i] = *(const s16x8*)(As + ((m << 3) + (q ^ (m & 7))) * 8);
                int n = hn + i * 16 + lm;
                wf[i] = *(const s16x8*)(Ws + ((n << 3) + (q ^ (n & 7))) * 8);
            }
            #pragma unroll
            for (int i = 0; i < 4; ++i)
                #pragma unroll
                for (int j = 0; j < 4; ++j)
                    acc[i][j] = __builtin_amdgcn_mfma_f32_16x16x32_bf16(
                        af[i], wf[j], acc[i][j], 0, 0, 0);
        }
    }

    // epilogue: unit u = ((n0+hn)>>6)*16 + lm; gate g = j.
    const int u = ((n0 + hn) >> 6) * 16 + lm;
    int pc[4];
    float bv[4];
    #pragma unroll
    for (int g = 0; g < 4; ++g) {
        pc[g] = n0 + hn + g * 16 + lm;
        bv[g] = biasp[pc[g]];
    }
    #pragma unroll
    for (int i = 0; i < 4; ++i) {
        #pragma unroll
        for (int rr = 0; rr < 4; ++rr) {
            int b = m0 + hm + i * 16 + quad * 4 + rr;
            const __hip_bfloat16* xr = Xg + (size_t)tok[b] * G4c;
            float gi = acc[i][0][rr] + bv[0] + __bfloat162float(xr[pc[0]]);
            float gf = acc[i][1][rr] + bv[1] + __bfloat162float(xr[pc[1]]);
            float gg = acc[i][2][rr] + bv[2] + __bfloat162float(xr[pc[2]]);
            float go = acc[i][3][rr] + bv[3] + __bfloat162float(xr[pc[3]]);
            float si = 1.0f / (1.0f + expf(-gi));
            float sf = 1.0f / (1.0f + expf(-gf));
            float so = 1.0f / (1.0f + expf(-go));
            size_t cix = (size_t)b * Hc + u;
            float cc = sf * cr[cix] + si * tanhf(gg);
            cr[cix] = cc;
            xh_out[(size_t)b * RLD + Ec + u] = __float2bfloat16(so * tanhf(cc));
        }
    }
}

__global__ __launch_bounds__(256) void gemm_recv_final(
    const __hip_bfloat16* __restrict__ A, const __hip_bfloat16* __restrict__ W,
    const float* __restrict__ biasp, const __hip_bfloat16* __restrict__ Xg,
    const int* __restrict__ tok, float* __restrict__ cr,
    __hip_bfloat16* __restrict__ xh_out)
{
    __shared__ GemmSmem sm;
    recv_gemm_cell_body(sm, A, W, biasp, Xg, tok, cr, xh_out,
                        blockIdx.x & 31, blockIdx.x >> 5);
}

__global__ __launch_bounds__(256) void gemm_bf16_tn(
    const __hip_bfloat16* __restrict__ A, int lda,
    const __hip_bfloat16* __restrict__ W, int ldw,
    const float* __restrict__ bias, float* __restrict__ C,
    int M, int N, int K, float* __restrict__ tile_max, int tmld)
{
    __shared__ GemmSmem sm;
    gemm_body<0>(sm, A, lda, W, ldw, bias, C, M, N, K, blockIdx.x, blockIdx.y,
                 tile_max, tmld);
}

// split-K x2: blockIdx.z selects K-half; fp32 partials, no bias.
__global__ __launch_bounds__(256) void gemm_bf16_sk2(
    const __hip_bfloat16* __restrict__ A, int lda,
    const __hip_bfloat16* __restrict__ W, int ldw,
    float* __restrict__ Cpart, int M, int N, int Ksub)
{
    __shared__ GemmSmem sm;
    int z = blockIdx.z;
    gemm_body<0>(sm, A + (size_t)z * Ksub, lda, W + (size_t)z * Ksub, ldw,
                 nullptr, Cpart + (size_t)z * M * N, M, N, Ksub, blockIdx.x,
                 blockIdx.y, nullptr, 0);
}

// ---------------------------------------------------------------------------
// One-time table dispatch: Xg_s build (nbS blocks) || Xg_r build (nbR blocks)
// || h0 = target3 @ W_aff3^T split-K x2 (128 blocks).
// ---------------------------------------------------------------------------
__global__ __launch_bounds__(256) void gemm_tab_h0(
    int nbS, int nbR,
    const __hip_bfloat16* __restrict__ embS, const __hip_bfloat16* __restrict__ embR,
    const __hip_bfloat16* __restrict__ W3x, const __hip_bfloat16* __restrict__ Wr,
    __hip_bfloat16* __restrict__ XgS, __hip_bfloat16* __restrict__ XgR,
    const __hip_bfloat16* __restrict__ target3,
    const __hip_bfloat16* __restrict__ W_aff3, float* __restrict__ gates_p)
{
    __shared__ GemmSmem sm;
    int bid = blockIdx.x;
    if (bid < nbS) {
        gemm_body<1>(sm, embS, Ec, W3x, XLD, nullptr, XgS,
                     Vc, G4c, Ec, bid & 31, bid >> 5, nullptr, 0);
    } else if (bid < nbS + nbR) {
        int rem = bid - nbS;
        gemm_body<1>(sm, embR, Ec, Wr, RLD, nullptr, XgR,
                     Vc, G4c, Ec, rem & 31, rem >> 5, nullptr, 0);
    } else {
        int r2 = bid - nbS - nbR;     // 128 blocks: h0 sk2, Ksub=3072
        int z = r2 >> 6, rem = r2 & 63;
        gemm_body<0>(sm, target3 + (size_t)z * 3072, 6144,
                     W_aff3 + (size_t)z * 3072, 6144, nullptr,
                     gates_p + (size_t)z * Bc * Hc,
                     Bc, Hc, 3072, rem & 7, rem >> 3, nullptr, 0);
    }
}

// ---------------------------------------------------------------------------
// Fused per-step GEMM dispatch:
//   blocks [0, nb_g):       sender gates(t+1) split-K x2 (z = bid>>8,
//                           Ksub=1536, 24 K-iters) -> gates_p halves 0/1
//   blocks [nb_g, +632):    logits(t)+tilemax (16 iters; bf16 out if LOGBF)
// 1144 blocks at 32KB LDS -> 5 blocks/CU -> all co-resident.
// ---------------------------------------------------------------------------
template<int LOGBF>
__global__ __launch_bounds__(256) void gemm_fused_step(
    int nb_g,
    const __hip_bfloat16* __restrict__ Ag, const __hip_bfloat16* __restrict__ Wg,
    float* __restrict__ Cg,
    const __hip_bfloat16* __restrict__ Al, const __hip_bfloat16* __restrict__ Wl,
    const float* __restrict__ bl, void* __restrict__ Cl,
    float* __restrict__ tmax)
{
    __shared__ GemmSmem sm;
    int bid = blockIdx.x;
    if (bid < nb_g) {
        int z = bid >> 8, rem = bid & 255;
        gemm_body<0>(sm, Ag + (size_t)z * 1536, XLD, Wg + (size_t)z * 1536, XLD,
                     nullptr, Cg + (size_t)z * Bc * G4c,
                     Bc, G4c, 1536, rem & 31, rem >> 5, nullptr, 0);
    } else {
        int rem = bid - nb_g;
        int by = rem / NTv, bx = rem - by * NTv;
        gemm_body<LOGBF>(sm, Al, XLD, Wl, Hc, bl, Cl, Bc, Vc, Hc, bx, by,
                         tmax, TMLD);
    }
}

// ===========================================================================
// prep_all: ALL one-time elementwise prep in a single dispatch.
// ===========================================================================
#define PC0  2097152    // Wih_s cast -> W3x[:,0:512)
#define PC1  6291456    // + Whh_s split3 -> W3x[:,512:3584)
#define PC2  16531456   // + Wp cast
#define PC3  18628608   // + target split3_a -> target3 (ld 6144)
#define PC4  20725760   // + W_aff split3_w -> W_aff3 (ld 6144)
#define PC5  22822912   // + Wih_r perm cast -> WihWhh_r[:,0:512)
#define PC6  27017216   // + Whh_r perm cast -> WihWhh_r[:,512:1536)
#define PC7  29114368   // + W_out cast
#define PC8  29118464   // + bias_s add
#define PC9  29122560   // + bias_r perm add
#define PC10 34242560   // + emb_s cast
#define PC11 39362560   // + emb_r cast          (base grid)
#define PC12 41459712   // + target cast -> A4b
#define PC13 47751168   // + distr cast -> A4b+B*NIF  (extra grid)

__global__ __launch_bounds__(256) void prep_all_kernel(
    const float* __restrict__ Wih_s, const float* __restrict__ Whh_s,
    const float* __restrict__ Wp, const float* __restrict__ target,
    const float* __restrict__ W_aff, const float* __restrict__ Wih_r,
    const float* __restrict__ Whh_r, const float* __restrict__ W_out,
    const float* __restrict__ bih_s, const float* __restrict__ bhh_s,
    const float* __restrict__ bih_r, const float* __restrict__ bhh_r,
    const float* __restrict__ emb_s, const float* __restrict__ emb_r,
    const float* __restrict__ distr,
    __hip_bfloat16* __restrict__ W3x, __hip_bfloat16* __restrict__ Wp_b,
    __hip_bfloat16* __restrict__ target3, __hip_bfloat16* __restrict__ W_aff3,
    __hip_bfloat16* __restrict__ WihWhh_r, __hip_bfloat16* __restrict__ W_out_b,
    float* __restrict__ bias_s, float* __restrict__ bias_r,
    __hip_bfloat16* __restrict__ embS, __hip_bfloat16* __restrict__ embR,
    __hip_bfloat16* __restrict__ A4b)
{
    int i = blockIdx.x * 256 + threadIdx.x;
    if (i < PC0) {
        W3x[(size_t)(i / Ec) * XLD + (i % Ec)] = __float2bfloat16(Wih_s[i]);
    } else if (i < PC1) {
        int k = i - PC0; int m = k / Hc, c = k - m * Hc;
        float v = Whh_s[k];
        __hip_bfloat16 hi = __float2bfloat16(v);
        float lo = v - __bfloat162float(hi);
        __hip_bfloat16* row = W3x + (size_t)m * XLD + XOFF;
        row[c] = hi; row[Hc + c] = hi; row[2 * Hc + c] = __float2bfloat16(lo);
    } else if (i < PC2) {
        int k = i - PC1;
        Wp_b[k] = __float2bfloat16(Wp[k]);
    } else if (i < PC3) {
        int k = i - PC2; int m = k / NIFc, c = k - m * NIFc;
        float v = target[k];
        __hip_bfloat16 hi = __float2bfloat16(v);
        float lo = v - __bfloat162float(hi);
        __hip_bfloat16* row = target3 + (size_t)m * 6144;
        row[c] = hi; row[NIFc + c] = __float2bfloat16(lo); row[2 * NIFc + c] = hi;
    } else if (i < PC4) {
        int k = i - PC3; int m = k / NIFc, c = k - m * NIFc;
        float v = W_aff[k];
        __hip_bfloat16 hi = __float2bfloat16(v);
        float lo = v - __bfloat162float(hi);
        __hip_bfloat16* row = W_aff3 + (size_t)m * 6144;
        row[c] = hi; row[NIFc + c] = hi; row[2 * NIFc + c] = __float2bfloat16(lo);
    } else if (i < PC5) {
        int k = i - PC4; int p = k / Ec, c = k - p * Ec;
        WihWhh_r[(size_t)p * RLD + c] =
            __float2bfloat16(Wih_r[(size_t)rperm_orig(p) * Ec + c]);
    } else if (i < PC6) {
        int k = i - PC5; int p = k / Hc, c = k - p * Hc;
        WihWhh_r[(size_t)p * RLD + Ec + c] =
            __float2bfloat16(Whh_r[(size_t)rperm_orig(p) * Hc + c]);
    } else if (i < PC7) {
        int k = i - PC6;
        W_out_b[k] = __float2bfloat16(W_out[k]);
    } else if (i < PC8) {
        int k = i - PC7;
        bias_s[k] = bih_s[k] + bhh_s[k];
    } else if (i < PC9) {
        int k = i - PC8; int s = rperm_orig(k);
        bias_r[k] = bih_r[s] + bhh_r[s];
    } else if (i < PC10) {
        int k = i - PC9;
        embS[k] = __float2bfloat16(emb_s[k]);
    } else if (i < PC11) {
        int k = i - PC10;
        embR[k] = __float2bfloat16(emb_r[k]);
    } else if (i < PC12) {
        int k = i - PC11;
        A4b[k] = __float2bfloat16(target[k]);
    } else if (i < PC13) {
        int k = i - PC12;
        A4b[(size_t)Bc * NIFc + k] = __float2bfloat16(distr[k]);
    }
}

__global__ __launch_bounds__(256) void cast2d_kernel(
    const float* __restrict__ in, int ldin,
    __hip_bfloat16* __restrict__ out, int ldo, int coff, int M, int K)
{
    int i = blockIdx.x * 256 + threadIdx.x;
    if (i >= M * K) return;
    int m = i / K, k = i - m * K;
    out[(size_t)m * ldo + coff + k] = __float2bfloat16(in[(size_t)m * ldin + k]);
}

// gather token embedding, hi-only bf16 (fallback path)
__global__ __launch_bounds__(256) void gather_cast_kernel(
    const float* __restrict__ emb, int E, const int* __restrict__ idx,
    int stride, __hip_bfloat16* __restrict__ out, int ldo, int coff, int Brows)
{
    int i = blockIdx.x * 256 + threadIdx.x;
    if (i >= Brows * E) return;
    int b = i / E, k = i - b * E;
    out[(size_t)b * ldo + coff + k] =
        __float2bfloat16(emb[(size_t)idx[(size_t)b * stride] * E + k]);
}

// ===========================================================================
// LSTM pointwise helpers
// ===========================================================================
__device__ __forceinline__ short bf16bits(float x) {
    __hip_bfloat16 t = __float2bfloat16(x);
    return *reinterpret_cast<short*>(&t);
}

__device__ __forceinline__ float b16f(short s) {
    return __bfloat162float(*reinterpret_cast<__hip_bfloat16*>(&s));
}

// sender cell (standalone, step 0 + fallback)
__global__ __launch_bounds__(256) void lstm_fused_s(
    const float* __restrict__ gp0, const float* __restrict__ gp1,
    const float* __restrict__ bias, float* __restrict__ h,
    float* __restrict__ c, __hip_bfloat16* __restrict__ h3x,
    const __hip_bfloat16* __restrict__ xg, const int* __restrict__ tok,
    int tstride)
{
    int i = blockIdx.x * 256 + threadIdx.x;      // over Bc*Hc/4
    if (i >= Bc * Hc / 4) return;
    int b = i >> 8;
    int j = (i & 255) * 4;
    size_t g0 = (size_t)b * G4c + j;
    f32x4 gi = *(const f32x4*)(gp0 + g0) + *(const f32x4*)(gp1 + g0)
             + *(const f32x4*)(bias + j);
    f32x4 gf = *(const f32x4*)(gp0 + g0 + Hc) + *(const f32x4*)(gp1 + g0 + Hc)
             + *(const f32x4*)(bias + Hc + j);
    f32x4 gg = *(const f32x4*)(gp0 + g0 + 2 * Hc) + *(const f32x4*)(gp1 + g0 + 2 * Hc)
             + *(const f32x4*)(bias + 2 * Hc + j);
    f32x4 go = *(const f32x4*)(gp0 + g0 + 3 * Hc) + *(const f32x4*)(gp1 + g0 + 3 * Hc)
             + *(const f32x4*)(bias + 3 * Hc + j);
    if (xg) {
        const __hip_bfloat16* xr = xg + (size_t)tok[(size_t)b * tstride] * G4c;
        s16x4 xi = *(const s16x4*)(xr + j);
        s16x4 xf = *(const s16x4*)(xr + Hc + j);
        s16x4 xc = *(const s16x4*)(xr + 2 * Hc + j);
        s16x4 xo = *(const s16x4*)(xr + 3 * Hc + j);
        #pragma unroll
        for (int k = 0; k < 4; ++k) {
            gi[k] += b16f(xi[k]);
            gf[k] += b16f(xf[k]);
            gg[k] += b16f(xc[k]);
            go[k] += b16f(xo[k]);
        }
    }
    size_t hix = (size_t)b * Hc + j;
    f32x4 cv = *(const f32x4*)(c + hix);
    f32x4 cn, hv;
    s16x4 hi4, lo4;
    #pragma unroll
    for (int k = 0; k < 4; ++k) {
        float si = 1.0f / (1.0f + expf(-gi[k]));
        float sf = 1.0f / (1.0f + expf(-gf[k]));
        float so = 1.0f / (1.0f + expf(-go[k]));
        float cc = sf * cv[k] + si * tanhf(gg[k]);
        cn[k] = cc;
        float hh = so * tanhf(cc);
        hv[k] = hh;
        hi4[k] = bf16bits(hh);
        lo4[k] = bf16bits(hh - __bfloat162float(__float2bfloat16(hh)));
    }
    *(f32x4*)(c + hix) = cn;
    *(f32x4*)(h + hix) = hv;
    __hip_bfloat16* row = h3x + (size_t)b * XLD + XOFF;
    *(s16x4*)(row + j) = hi4;
    *(s16x4*)(row + Hc + j) = lo4;
    *(s16x4*)(row + 2 * Hc + j) = hi4;
}

__global__ __launch_bounds__(256) void combine_h0_kernel(
    const float* __restrict__ p0, const float* __restrict__ p1,
    const float* __restrict__ bias, float* __restrict__ h,
    __hip_bfloat16* __restrict__ h3x)
{
    int i = blockIdx.x * 256 + threadIdx.x;
    if (i >= Bc * Hc / 4) return;
    int b = i >> 8;
    int j = (i & 255) * 4;
    size_t ix = (size_t)b * Hc + j;
    f32x4 v = *(const f32x4*)(p0 + ix) + *(const f32x4*)(p1 + ix)
            + *(const f32x4*)(bias + j);
    *(f32x4*)(h + ix) = v;
    s16x4 hi4, lo4;
    #pragma unroll
    for (int k = 0; k < 4; ++k) {
        hi4[k] = bf16bits(v[k]);
        lo4[k] = bf16bits(v[k] - __bfloat162float(__float2bfloat16(v[k])));
    }
    __hip_bfloat16* row = h3x + (size_t)b * XLD + XOFF;
    *(s16x4*)(row + j) = hi4;
    *(s16x4*)(row + Hc + j) = lo4;
    *(s16x4*)(row + 2 * Hc + j) = hi4;
}

// receiver cell (fallback path only) — gates/bias/Xg in PERMUTED column order
__global__ __launch_bounds__(256) void lstm_fused_r(
    const float* __restrict__ gp0, const float* __restrict__ gp1,
    const float* __restrict__ bias, float* __restrict__ h,
    float* __restrict__ c, __hip_bfloat16* __restrict__ xh_r,
    const __hip_bfloat16* __restrict__ xg, const int* __restrict__ tok,
    int has_g, const float* __restrict__ emb, const int* __restrict__ msg_next)
{
    int i = blockIdx.x * 256 + threadIdx.x;
    if (i >= Bc * Hc / 4) return;
    int b = i >> 8;
    int j = (i & 255) * 4;                 // unit base, 4 consecutive units
    int pb = (j >> 4) * 64 + (j & 15);     // permuted col base (gate 0)
    f32x4 gi = *(const f32x4*)(bias + pb);
    f32x4 gf = *(const f32x4*)(bias + pb + 16);
    f32x4 gg = *(const f32x4*)(bias + pb + 32);
    f32x4 go = *(const f32x4*)(bias + pb + 48);
    if (has_g) {
        size_t g0 = (size_t)b * G4c + pb;
        gi += *(const f32x4*)(gp0 + g0) + *(const f32x4*)(gp1 + g0);
        gf += *(const f32x4*)(gp0 + g0 + 16) + *(const f32x4*)(gp1 + g0 + 16);
        gg += *(const f32x4*)(gp0 + g0 + 32) + *(const f32x4*)(gp1 + g0 + 32);
        go += *(const f32x4*)(gp0 + g0 + 48) + *(const f32x4*)(gp1 + g0 + 48);
    }
    if (xg) {
        const __hip_bfloat16* xr = xg + (size_t)tok[b] * G4c;
        s16x4 xi = *(const s16x4*)(xr + pb);
        s16x4 xf = *(const s16x4*)(xr + pb + 16);
        s16x4 xc = *(const s16x4*)(xr + pb + 32);
        s16x4 xo = *(const s16x4*)(xr + pb + 48);
        #pragma unroll
        for (int k = 0; k < 4; ++k) {
            gi[k] += b16f(xi[k]);
            gf[k] += b16f(xf[k]);
            gg[k] += b16f(xc[k]);
            go[k] += b16f(xo[k]);
        }
    }
    size_t hix = (size_t)b * Hc + j;
    f32x4 cv = *(const f32x4*)(c + hix);
    f32x4 cn, hv;
    s16x4 hb4;
    #pragma unroll
    for (int k = 0; k < 4; ++k) {
        float si = 1.0f / (1.0f + expf(-gi[k]));
        float sf = 1.0f / (1.0f + expf(-gf[k]));
        float so = 1.0f / (1.0f + expf(-go[k]));
        float cc = sf * cv[k] + si * tanhf(gg[k]);
        cn[k] = cc;
        float hh = so * tanhf(cc);
        hv[k] = hh;
        hb4[k] = bf16bits(hh);
    }
    *(f32x4*)(c + hix) = cn;
    *(f32x4*)(h + hix) = hv;
    *(s16x4*)(xh_r + (size_t)b * RLD + Ec + j) = hb4;
    if (!xg && msg_next && j < Ec) {
        int t2 = msg_next[b];
        f32x4 e = *(const f32x4*)(emb + (size_t)t2 * Ec + j);
        s16x4 eb;
        #pragma unroll
        for (int k = 0; k < 4; ++k) eb[k] = bf16bits(e[k]);
        *(s16x4*)(xh_r + (size_t)b * RLD + j) = eb;
    }
}

// ===========================================================================
// argmax v3 (fallback standalone version, fp32 logits)
// ===========================================================================
__global__ __launch_bounds__(256) void argmax_rescore_v3(
    const float* __restrict__ logits, const float* __restrict__ tmax,
    const float* __restrict__ h, const float* __restrict__ Wp,
    const float* __restrict__ bp, const float* __restrict__ emb,
    int* __restrict__ msg_t, float* __restrict__ logp,
    __hip_bfloat16* __restrict__ xdst, int want_logp)
{
    const int b = blockIdx.x;
    const int tid = threadIdx.x;
    const int lane = tid & 63;
    const int wave = tid >> 6;
    const float* row = logits + (size_t)b * Vc;

    __shared__ float stm[128];
    __shared__ float redm[256];
    __shared__ float reds[256];
    __shared__ int   qt[32];
    __shared__ int   nq, cnt;
    __shared__ int   cand[64];
    __shared__ float score[64];
    __shared__ float sbestv;
    __shared__ int   sbestj;

    float tv = (tid < NTv) ? tmax[(size_t)b * TMLD + tid] : -__builtin_inff();
    if (tid < 128) stm[tid] = tv;
    redm[tid] = tv;
    reds[tid] = (tid < NTv) ? tv : 0.0f;
    if (tid == 0) { nq = 0; cnt = 0; }
    __syncthreads();
    #pragma unroll
    for (int s = 128; s > 0; s >>= 1) {
        if (tid < s) {
            redm[tid] = fmaxf(redm[tid], redm[tid + s]);
            reds[tid] += reds[tid + s];
        }
        __syncthreads();
    }
    const float m = redm[0];
    const float spread = m - reds[0] * (1.0f / NTv);
    const float delta = 0.08f * spread + 1e-6f * (1.0f + fabsf(m));

    if (tid < NTv && stm[tid] >= m - delta) {
        int k = atomicAdd(&nq, 1);
        if (k < 32) qt[k] = tid;
    }
    __syncthreads();
    int nqt = nq < 32 ? nq : 32;

    for (int qi = 0; qi < nqt; qi += 2) {
        int ti = qi + (tid >> 7);
        if (ti < nqt) {
            int j = qt[ti] * 128 + (tid & 127);
            if (j < Vc) {
                float v = row[j];
                if (v >= m - delta) {
                    int k = atomicAdd(&cnt, 1);
                    if (k < 64) cand[k] = j;
                }
            }
        }
    }
    __syncthreads();
    int nc = cnt < 64 ? cnt : 64;

    const float* hrow = h + (size_t)b * Hc;
    for (int cix = wave; cix < nc; cix += 4) {
        int j = cand[cix];
        const float* wrow = Wp + (size_t)j * Hc;
        float part = 0.0f;
        #pragma unroll
        for (int kk = 0; kk < 4; ++kk) {
            int k = kk * 256 + lane * 4;
            f32x4 hv = *(const f32x4*)(hrow + k);
            f32x4 wv = *(const f32x4*)(wrow + k);
            part = fmaf(hv.x, wv.x, part);
            part = fmaf(hv.y, wv.y, part);
            part = fmaf(hv.z, wv.z, part);
            part = fmaf(hv.w, wv.w, part);
        }
        #pragma unroll
        for (int off = 1; off < 64; off <<= 1)
            part += __shfl_xor(part, off);
        if (lane == 0) score[cix] = part + bp[j];
    }
    __syncthreads();
    if (tid == 0) {
        float bv = -__builtin_inff();
        int bj = 0x7fffffff;
        for (int cix = 0; cix < nc; ++cix) {
            float v = score[cix];
            int j = cand[cix];
            if (v > bv || (v == bv && j < bj)) { bv = v; bj = j; }
        }
        sbestv = bv;
        sbestj = bj;
        msg_t[b] = bj;
    }
    __syncthreads();
    const int bestj = sbestj;

    if (want_logp) {
        float s = 0.0f;
        const f32x4* row4 = (const f32x4*)row;
        for (int j = tid; j < Vc / 4; j += 256) {
            f32x4 v = row4[j];
            s += expf(v.x - m) + expf(v.y - m) + expf(v.z - m) + expf(v.w - m);
        }
        redm[tid] = s;
        __syncthreads();
        #pragma unroll
        for (int st = 128; st > 0; st >>= 1) {
            if (tid < st) redm[tid] += redm[tid + st];
            __syncthreads();
        }
        if (tid == 0) logp[b] = sbestv - (m + logf(redm[0]));
    }

    if (xdst && tid < 128) {
        int k = tid * 4;
        f32x4 e = *(const f32x4*)(emb + (size_t)bestj * Ec + k);
        s16x4 h4;
        #pragma unroll
        for (int kk = 0; kk < 4; ++kk) h4[kk] = bf16bits(e[kk]);
        *(s16x4*)(xdst + (size_t)b * XLD + k) = h4;
    }
}

// ===========================================================================
// Combined per-step pointwise dispatch (1280 blocks, 32KB LDS -> 5/CU, all
// co-resident):
//   blocks [0, nb_r):    recv GEMM + fused cellR(t-1)
//   blocks [nb_r, +Bc):  argmax(t) + sender cell(t+1) for row b
// ALL scratch (incl. nq/cnt/best) carved from the single GemmSmem block.
// Sender gates are split-K x2: phase B sums gp0+gp1 partials.
// ===========================================================================
template<int LGBF>
__global__ __launch_bounds__(256) void argmax_cell_recv(
    int nb_r,
    const __hip_bfloat16* __restrict__ Ar, const __hip_bfloat16* __restrict__ Wr,
    const float* __restrict__ biasrp, const __hip_bfloat16* __restrict__ Xgr,
    const int* __restrict__ tokr, float* __restrict__ cr,
    __hip_bfloat16* __restrict__ xh_out,
    const void* __restrict__ logits_v, const float* __restrict__ tmax,
    const float* __restrict__ h, const float* __restrict__ Wp,
    const float* __restrict__ bp, int* __restrict__ msg_t,
    float* __restrict__ logp, int want_logp,
    int do_s, const float* __restrict__ gp0, const float* __restrict__ gp1,
    const float* __restrict__ bias_s, float* __restrict__ h_s,
    float* __restrict__ c_s, __hip_bfloat16* __restrict__ h3x,
    const __hip_bfloat16* __restrict__ Xg_s)
{
    __shared__ GemmSmem sm;

    if ((int)blockIdx.x < nb_r) {
        recv_gemm_cell_body(sm, Ar, Wr, biasrp, Xgr, tokr, cr, xh_out,
                            blockIdx.x & 31, blockIdx.x >> 5);
        return;
    }
    const int b = blockIdx.x - nb_r;
    const int tid = threadIdx.x;
    const int lane = tid & 63;
    const int wave = tid >> 6;
    const __hip_bfloat16* rowb = (const __hip_bfloat16*)logits_v + (size_t)b * Vc;
    const float* rowf = (const float*)logits_v + (size_t)b * Vc;

    // carve argmax scratch from the GemmSmem storage (~3.2 KB of 16 KB As)
    float* stm  = (float*)sm.As;
    float* redm = stm + 128;
    float* reds = redm + 256;
    int*   qt   = (int*)(reds + 256);
    int*   cand = qt + 32;
    float* score= (float*)(cand + 64);
    int*   pnq  = (int*)(score + 64);
    int*   pcnt = pnq + 1;
    int*   pbj  = pcnt + 1;
    float* pbv  = (float*)(pbj + 1);

    // ---------------- phase A: argmax ----------------
    float tv = (tid < NTv) ? tmax[(size_t)b * TMLD + tid] : -__builtin_inff();
    if (tid < 128) stm[tid] = tv;
    redm[tid] = tv;
    reds[tid] = (tid < NTv) ? tv : 0.0f;
    if (tid == 0) { *pnq = 0; *pcnt = 0; }
    __syncthreads();
    #pragma unroll
    for (int s = 128; s > 0; s >>= 1) {
        if (tid < s) {
            redm[tid] = fmaxf(redm[tid], redm[tid + s]);
            reds[tid] += reds[tid + s];
        }
        __syncthreads();
    }
    const float m = redm[0];
    const float spread = m - reds[0] * (1.0f / NTv);
    const float delta = 0.08f * spread + 1e-6f * (1.0f + fabsf(m));

    if (tid < NTv && stm[tid] >= m - delta) {
        int k = atomicAdd(pnq, 1);
        if (k < 32) qt[k] = tid;
    }
    __syncthreads();
    int nqt = *pnq < 32 ? *pnq : 32;

    for (int qi = 0; qi < nqt; qi += 2) {
        int ti = qi + (tid >> 7);
        if (ti < nqt) {
            int j = qt[ti] * 128 + (tid & 127);
            if (j < Vc) {
                float v = LGBF ? __bfloat162float(rowb[j]) : rowf[j];
                if (v >= m - delta) {
                    int k = atomicAdd(pcnt, 1);
                    if (k < 64) cand[k] = j;
                }
            }
        }
    }
    __syncthreads();
    int nc = *pcnt < 64 ? *pcnt : 64;   // >=1: stored max qualifies

    const float* hrow = h + (size_t)b * Hc;
    for (int cix = wave; cix < nc; cix += 4) {
        int j = cand[cix];
        const float* wrow = Wp + (size_t)j * Hc;
        float part = 0.0f;
        #pragma unroll
        for (int kk = 0; kk < 4; ++kk) {
            int k = kk * 256 + lane * 4;
            f32x4 hv = *(const f32x4*)(hrow + k);
            f32x4 wv = *(const f32x4*)(wrow + k);
            part = fmaf(hv.x, wv.x, part);
            part = fmaf(hv.y, wv.y, part);
            part = fmaf(hv.z, wv.z, part);
            part = fmaf(hv.w, wv.w, part);
        }
        #pragma unroll
        for (int off = 1; off < 64; off <<= 1)
            part += __shfl_xor(part, off);
        if (lane == 0) score[cix] = part + bp[j];
    }
    __syncthreads();
    if (tid == 0) {
        float bv = -__builtin_inff();
        int bj = 0x7fffffff;
        for (int cix = 0; cix < nc; ++cix) {
            float v = score[cix];
            int j = cand[cix];
            if (v > bv || (v == bv && j < bj)) { bv = v; bj = j; }
        }
        *pbv = bv;
        *pbj = bj;
        msg_t[b] = bj;
    }
    __syncthreads();
    const int tok = *pbj;
    const float bestv = *pbv;

    if (!LGBF && want_logp) {
        float s = 0.0f;
        const f32x4* row4 = (const f32x4*)rowf;
        for (int j = tid; j < Vc / 4; j += 256) {
            f32x4 v = row4[j];
            s += expf(v.x - m) + expf(v.y - m) + expf(v.z - m) + expf(v.w - m);
        }
        redm[tid] = s;
        __syncthreads();
        #pragma unroll
        for (int st = 128; st > 0; st >>= 1) {
            if (tid < st) redm[tid] += redm[tid + st];
            __syncthreads();
        }
        if (tid == 0) logp[b] = bestv - (m + logf(redm[0]));
        __syncthreads();
    }

    // ---------------- phase B: sender lstm (t+1), row b ----------------
    if (do_s) {
        const int j = tid * 4;
        size_t g0 = (size_t)b * G4c + j;
        f32x4 gi = *(const f32x4*)(gp0 + g0) + *(const f32x4*)(gp1 + g0)
                 + *(const f32x4*)(bias_s + j);
        f32x4 gf = *(const f32x4*)(gp0 + g0 + Hc) + *(const f32x4*)(gp1 + g0 + Hc)
                 + *(const f32x4*)(bias_s + Hc + j);
        f32x4 gg = *(const f32x4*)(gp0 + g0 + 2 * Hc) + *(const f32x4*)(gp1 + g0 + 2 * Hc)
                 + *(const f32x4*)(bias_s + 2 * Hc + j);
        f32x4 go = *(const f32x4*)(gp0 + g0 + 3 * Hc) + *(const f32x4*)(gp1 + g0 + 3 * Hc)
                 + *(const f32x4*)(bias_s + 3 * Hc + j);
        const __hip_bfloat16* xr = Xg_s + (size_t)tok * G4c;
        s16x4 xi = *(const s16x4*)(xr + j);
        s16x4 xf = *(const s16x4*)(xr + Hc + j);
        s16x4 xc = *(const s16x4*)(xr + 2 * Hc + j);
        s16x4 xo = *(const s16x4*)(xr + 3 * Hc + j);
        size_t hix = (size_t)b * Hc + j;
        f32x4 cv = *(const f32x4*)(c_s + hix);
        f32x4 cn, hv;
        s16x4 hi4, lo4;
        #pragma unroll
        for (int k = 0; k < 4; ++k) {
            float gik = gi[k] + b16f(xi[k]);
            float gfk = gf[k] + b16f(xf[k]);
            float ggk = gg[k] + b16f(xc[k]);
            float gok = go[k] + b16f(xo[k]);
            float si = 1.0f / (1.0f + expf(-gik));
            float sf = 1.0f / (1.0f + expf(-gfk));
            float so = 1.0f / (1.0f + expf(-gok));
            float cc = sf * cv[k] + si * tanhf(ggk);
            cn[k] = cc;
            float hh = so * tanhf(cc);
            hv[k] = hh;
            hi4[k] = bf16bits(hh);
            lo4[k] = bf16bits(hh - __bfloat162float(__float2bfloat16(hh)));
        }
        *(f32x4*)(c_s + hix) = cn;
        *(f32x4*)(h_s + hix) = hv;
        __hip_bfloat16* orow = h3x + (size_t)b * XLD + XOFF;
        *(s16x4*)(orow + j) = hi4;
        *(s16x4*)(orow + Hc + j) = lo4;
        *(s16x4*)(orow + 2 * Hc + j) = hi4;
    }
}

// ===========================================================================
// Hinge loss partial reduction; S layout [4][B][B]
// ===========================================================================
__global__ __launch_bounds__(256) void hinge_kernel(
    const float* __restrict__ S, const float* __restrict__ logp,
    float* __restrict__ partials, int Bn)
{
    int tid = threadIdx.x;
    int n = Bn * Bn;
    float acc = 0.0f;
    for (int idx = blockIdx.x * 256 + tid; idx < n; idx += gridDim.x * 256) {
        int j = idx & (Bn - 1);
        float s0 = S[idx];
        float l = fmaxf(0.0f, 1.0f - s0 + S[n + idx])
                + fmaxf(0.0f, 1.0f - s0 + S[2 * n + idx])
                + fmaxf(0.0f, 1.0f - s0 + S[3 * n + idx]);
        acc += l * logp[j];
    }
    __shared__ float sv[256];
    sv[tid] = acc;
    __syncthreads();
    for (int s = 128; s > 0; s >>= 1) {
        if (tid < s) sv[tid] += sv[tid + s];
        __syncthreads();
    }
    if (tid == 0) partials[blockIdx.x] = sv[0];
}

__global__ __launch_bounds__(256) void final_reduce_kernel(
    const float* __restrict__ partials, int np, float* __restrict__ out,
    float scale)
{
    int tid = threadIdx.x;
    float acc = 0.0f;
    for (int i = tid; i < np; i += 256) acc += partials[i];
    __shared__ float sv[256];
    sv[tid] = acc;
    __syncthreads();
    for (int s = 128; s > 0; s >>= 1) {
        if (tid < s) sv[tid] += sv[tid + s];
        __syncthreads();
    }
    if (tid == 0) out[0] = sv[0] * scale;
}

// ===========================================================================
extern "C" void kernel_launch(void* const* d_in, const int* in_sizes, int n_in,
                              void* d_out, int out_size, void* d_ws, size_t ws_size,
                              hipStream_t stream)
{
    (void)in_sizes; (void)n_in; (void)out_size;

    const float* target  = (const float*)d_in[0];
    const float* distr   = (const float*)d_in[1];
    const int*   start_t = (const int*)d_in[2];
    const float* W_aff = (const float*)d_in[4];
    const float* b_aff = (const float*)d_in[5];
    const float* emb_s = (const float*)d_in[6];
    const float* Wih_s = (const float*)d_in[7];
    const float* Whh_s = (const float*)d_in[8];
    const float* bih_s = (const float*)d_in[9];
    const float* bhh_s = (const float*)d_in[10];
    const float* Wp    = (const float*)d_in[11];
    const float* bp    = (const float*)d_in[12];
    const float* emb_r = (const float*)d_in[13];
    const float* Wih_r = (const float*)d_in[14];
    const float* Whh_r = (const float*)d_in[15];
    const float* bih_r = (const float*)d_in[16];
    const float* bhh_r = (const float*)d_in[17];
    const float* W_out = (const float*)d_in[18];
    const float* b_out = (const float*)d_in[19];

    dim3 blk(256);

    // ---------------- workspace layout ----------------
    char* b0 = (char*)d_ws;
    size_t off = 0;
    auto take = [&](size_t bytes) -> char* {
        char* p = b0 + off;
        off += (bytes + 511) & ~(size_t)511;
        return p;
    };
    const size_t MB = 1024 * 1024;
    __hip_bfloat16* W3x     = (__hip_bfloat16*)take((size_t)G4c * XLD * 2);
    __hip_bfloat16* Wp_b    = (__hip_bfloat16*)take((size_t)Vc * Hc * 2);
    __hip_bfloat16* WihWhh_r= (__hip_bfloat16*)take((size_t)G4c * RLD * 2); // PERM rows
    __hip_bfloat16* W_out_b = (__hip_bfloat16*)take((size_t)NIFc * Hc * 2);
    __hip_bfloat16* h3x     = (__hip_bfloat16*)take((size_t)Bc * XLD * 2);
    __hip_bfloat16* xh_rA   = (__hip_bfloat16*)take((size_t)Bc * RLD * 2);
    __hip_bfloat16* xh_rB   = (__hip_bfloat16*)take((size_t)Bc * RLD * 2);
    float* gates_p = (float*)take((size_t)2 * Bc * G4c * 4);  // sk2 halves
    float* h_s    = (float*)take((size_t)Bc * Hc * 4);
    float* c_s    = (float*)take((size_t)Bc * Hc * 4);
    float* hr     = (float*)take((size_t)Bc * Hc * 4);
    float* cr     = (float*)take((size_t)Bc * Hc * 4);
    float* logp   = (float*)take(Bc * 4);
    int*   msg    = (int*)take((size_t)Lc * Bc * 4);
    float* parts  = (float*)take(1024 * 4);
    float* bias_s = (float*)take(G4c * 4);
    float* bias_r = (float*)take(G4c * 4);   // PERMUTED content
    float* tilemax= (float*)take((size_t)Bc * TMLD * 4);
    char*  U      = take(48 * MB);

    // Optional precomputed x-gate tables (gated on ws_size).
    __hip_bfloat16* Xg_s = (__hip_bfloat16*)take((size_t)Vc * G4c * 2);
    const int use_tab_s = (off <= ws_size);
    __hip_bfloat16* Xg_r = (__hip_bfloat16*)take((size_t)Vc * G4c * 2); // PERM cols
    const int use_tab_r = (off <= ws_size);
    const int use_merged = use_tab_s && use_tab_r;
    // Optional dedicated sim-GEMM buffers -> A4b/distr casts fold into prep_all
    __hip_bfloat16* A4b_ws = (__hip_bfloat16*)take((size_t)4 * Bc * NIFc * 2);
    __hip_bfloat16* r_b_ws = (__hip_bfloat16*)take((size_t)Bc * NIFc * 2);
    const int use_extra = (off <= ws_size);

    // U sub-layout (phased reuse)
    __hip_bfloat16* target3 = (__hip_bfloat16*)U;                 // phase 1
    __hip_bfloat16* W_aff3  = (__hip_bfloat16*)(U + 13 * MB);     // phase 1
    __hip_bfloat16* emb_bS  = (__hip_bfloat16*)(U + 26 * MB);     // phase 1
    __hip_bfloat16* emb_bR  = (__hip_bfloat16*)(U + 36 * MB);     // phase 1
    float*          logits  = (float*)U;                          // phase 2
    __hip_bfloat16* A4b_u   = (__hip_bfloat16*)U;                 // phase 3 (fallback)
    float*          r_f     = (float*)(U + 17 * MB);              // phase 3
    __hip_bfloat16* r_b_u   = (__hip_bfloat16*)(U + 26 * MB);     // phase 3 (fallback)
    float*          S       = (float*)(U + 31 * MB);              // phase 3

    __hip_bfloat16* A4b = use_extra ? A4b_ws : A4b_u;
    __hip_bfloat16* r_b = use_extra ? r_b_ws : r_b_u;

    // ---- ALL one-time elementwise prep in ONE dispatch ----
    const int base_blocks  = (PC11 + 255) / 256;
    const int extra_blocks = (PC13 + 255) / 256;
    prep_all_kernel<<<use_extra ? extra_blocks : base_blocks, blk, 0, stream>>>(
        Wih_s, Whh_s, Wp, target, W_aff, Wih_r, Whh_r, W_out,
        bih_s, bhh_s, bih_r, bhh_r, emb_s, emb_r, distr,
        W3x, Wp_b, target3, W_aff3, WihWhh_r, W_out_b, bias_s, bias_r,
        emb_bS, emb_bR, A4b);

    // ---- Xg_s || Xg_r || h0 GEMMs in ONE dispatch ----
    const int nbS = use_tab_s ? 2528 : 0;
    const int nbR = use_tab_r ? 2528 : 0;
    gemm_tab_h0<<<nbS + nbR + 128, blk, 0, stream>>>(
        nbS, nbR, emb_bS, emb_bR, W3x, WihWhh_r, Xg_s, Xg_r,
        target3, W_aff3, gates_p);

    combine_h0_kernel<<<(Bc * Hc / 4 + 255) / 256, blk, 0, stream>>>(
        gates_p, gates_p + (size_t)Bc * Hc, b_aff, h_s, h3x);
    hipMemsetAsync(c_s, 0, (size_t)Bc * Hc * 4, stream);

    if (use_merged) {
        // ================= merged sender+receiver pipeline =================
        hipMemsetAsync(cr, 0, (size_t)Bc * Hc * 4, stream);
        hipMemsetAsync(xh_rA, 0, (size_t)Bc * RLD * 2, stream);   // R_0 = 0

        // step 0: gates(0) (sk2) + lstm_s(0) with start token
        gemm_bf16_sk2<<<dim3(G4c / GBN, Bc / GBM, 2), blk, 0, stream>>>(
            h3x + XOFF, XLD, W3x + XOFF, XLD, gates_p, Bc, G4c, 1536);
        lstm_fused_s<<<(Bc * Hc / 4 + 255) / 256, blk, 0, stream>>>(
            gates_p, gates_p + (size_t)Bc * G4c, bias_s, h_s, c_s, h3x,
            Xg_s, start_t, 0);

        for (int t = 0; t < Lc; ++t) {
            const int nb_g = (t < Lc - 1) ? 512 : 0;   // sk2 sender gates(t+1)
            const int nb_r = (t >= 1) ? 256 : 0;       // recv cellR(t-1)
            const int k = t - 1;
            const __hip_bfloat16* rin = (k & 1) ? xh_rB : xh_rA;
            __hip_bfloat16* rout = (k & 1) ? xh_rA : xh_rB;
            if (t < Lc - 1) {
                gemm_fused_step<1><<<nb_g + 632, blk, 0, stream>>>(
                    nb_g,
                    h3x + XOFF, W3x + XOFF, gates_p,
                    h3x + XOFF, Wp_b, bp, (void*)logits, tilemax);
                argmax_cell_recv<1><<<nb_r + Bc, blk, 0, stream>>>(
                    nb_r, rin + Ec, WihWhh_r + Ec, bias_r, Xg_r,
                    (t >= 1) ? msg + (t - 1) * Bc : msg, cr, rout,
                    (const void*)logits, tilemax, h_s, Wp, bp, msg + t * Bc,
                    logp, 0, 1, gates_p, gates_p + (size_t)Bc * G4c,
                    bias_s, h_s, c_s, h3x, Xg_s);
            } else {
                gemm_fused_step<0><<<632, blk, 0, stream>>>(
                    0,
                    h3x + XOFF, W3x + XOFF, gates_p,
                    h3x + XOFF, Wp_b, bp, (void*)logits, tilemax);
                argmax_cell_recv<0><<<nb_r + Bc, blk, 0, stream>>>(
                    nb_r, rin + Ec, WihWhh_r + Ec, bias_r, Xg_r,
                    msg + (t - 1) * Bc, cr, rout,
                    (const void*)logits, tilemax, h_s, Wp, bp, msg + t * Bc,
                    logp, 1, 0, gates_p, gates_p + (size_t)Bc * G4c,
                    bias_s, h_s, c_s, h3x, Xg_s);
            }
        }
        // final receiver app k=31: reads xh_rB (R_31), writes xh_rA (R_32)
        gemm_recv_final<<<256, blk, 0, stream>>>(
            xh_rB + Ec, WihWhh_r + Ec, bias_r, Xg_r, msg + (Lc - 1) * Bc,
            cr, xh_rA);
    } else {
        // ================= fallback: serial structure =================
        if (!use_tab_s)
            gather_cast_kernel<<<(Bc * Ec + 255) / 256, blk, 0, stream>>>(
                emb_s, Ec, start_t, 0, h3x, XLD, 0, Bc);

        for (int t = 0; t < Lc; ++t) {
            if (use_tab_s) {
                gemm_bf16_sk2<<<dim3(G4c / GBN, Bc / GBM, 2), blk, 0, stream>>>(
                    h3x + XOFF, XLD, W3x + XOFF, XLD, gates_p, Bc, G4c, 1536);
                lstm_fused_s<<<(Bc * Hc / 4 + 255) / 256, blk, 0, stream>>>(
                    gates_p, gates_p + (size_t)Bc * G4c, bias_s, h_s, c_s, h3x,
                    Xg_s, (t == 0) ? start_t : (msg + (t - 1) * Bc),
                    (t == 0) ? 0 : 1);
            } else {
                gemm_bf16_sk2<<<dim3(G4c / GBN, Bc / GBM, 2), blk, 0, stream>>>(
                    h3x, XLD, W3x, XLD, gates_p, Bc, G4c, 1792);
                lstm_fused_s<<<(Bc * Hc / 4 + 255) / 256, blk, 0, stream>>>(
                    gates_p, gates_p + (size_t)Bc * G4c, bias_s, h_s, c_s, h3x,
                    nullptr, nullptr, 0);
            }
            gemm_bf16_tn<<<dim3((Vc + GBN - 1) / GBN, Bc / GBM), blk, 0, stream>>>(
                h3x + XOFF, XLD, Wp_b, Hc, bp, logits, Bc, Vc, Hc, tilemax, TMLD);
            argmax_rescore_v3<<<Bc, blk, 0, stream>>>(
                logits, tilemax, h_s, Wp, bp, emb_s, msg + t * Bc, logp,
                (!use_tab_s && t < Lc - 1) ? h3x : nullptr,
                (t == Lc - 1) ? 1 : 0);
        }

        hipMemsetAsync(hr, 0, (size_t)Bc * Hc * 4, stream);
        hipMemsetAsync(cr, 0, (size_t)Bc * Hc * 4, stream);
        hipMemsetAsync(xh_rA, 0, (size_t)Bc * RLD * 2, stream);
        if (!use_tab_r)
            gather_cast_kernel<<<(Bc * Ec + 255) / 256, blk, 0, stream>>>(
                emb_r, Ec, msg, 1, xh_rA, RLD, 0, Bc);
        for (int t = 0; t < Lc; ++t) {
            if (use_tab_r) {
                if (t > 0)
                    gemm_bf16_sk2<<<dim3(G4c / GBN, Bc / GBM, 2), blk, 0, stream>>>(
                        xh_rA + Ec, RLD, WihWhh_r + Ec, RLD, gates_p, Bc, G4c, 512);
                lstm_fused_r<<<(Bc * Hc / 4 + 255) / 256, blk, 0, stream>>>(
                    gates_p, gates_p + (size_t)Bc * G4c, bias_r, hr, cr, xh_rA,
                    Xg_r, msg + t * Bc, (t > 0) ? 1 : 0, nullptr, nullptr);
            } else {
                gemm_bf16_sk2<<<dim3(G4c / GBN, Bc / GBM, 2), blk, 0, stream>>>(
                    xh_rA, RLD, WihWhh_r, RLD, gates_p, Bc, G4c, 768);
                lstm_fused_r<<<(Bc * Hc / 4 + 255) / 256, blk, 0, stream>>>(
                    gates_p, gates_p + (size_t)Bc * G4c, bias_r, hr, cr, xh_rA,
                    nullptr, nullptr, 1, emb_r,
                    (t < Lc - 1) ? (msg + (t + 1) * Bc) : nullptr);
            }
        }
    }

    // ---- r = hR_final @ W_out^T + b_out (final state is in xh_rA) ----
    gemm_bf16_tn<<<dim3(NIFc / GBN, Bc / GBM), blk, 0, stream>>>(
        xh_rA + Ec, RLD, W_out_b, Hc, b_out, r_f, Bc, NIFc, Hc, nullptr, 0);

    // ---- similarities: [target; distractors] @ r^T in ONE GEMM ----
    if (!use_extra) {
        cast2d_kernel<<<(Bc * NIFc + 255) / 256, blk, 0, stream>>>(
            target, NIFc, A4b, NIFc, 0, Bc, NIFc);
        cast2d_kernel<<<(NDc * Bc * NIFc + 255) / 256, blk, 0, stream>>>(
            distr, NIFc, A4b + (size_t)Bc * NIFc, NIFc, 0, NDc * Bc, NIFc);
    }
    cast2d_kernel<<<(Bc * NIFc + 255) / 256, blk, 0, stream>>>(
        r_f, NIFc, r_b, NIFc, 0, Bc, NIFc);
    gemm_bf16_tn<<<dim3(Bc / GBN, 4 * Bc / GBM), blk, 0, stream>>>(
        A4b, NIFc, r_b, NIFc, nullptr, S, 4 * Bc, Bc, NIFc, nullptr, 0);

    hinge_kernel<<<1024, blk, 0, stream>>>(S, logp, parts, Bc);
    final_reduce_kernel<<<1, blk, 0, stream>>>(
        parts, 1024, (float*)d_out, -1.0f / ((float)Bc * (float)Bc));
}

// Round 8
// 4479.799 us; speedup vs baseline: 1.0021x; 1.0021x over previous
//
#include <hip/hip_runtime.h>
#include <hip/hip_bf16.h>
#include <cstdint>
#include <cstddef>

// Problem constants (fixed by setup_inputs in the reference)
#define Bc   1024
#define NIFc 2048
#define Vc   10000
#define Ec   512
#define Hc   1024
#define Lc   32
#define NDc  3
#define G4c  4096   // 4*H
#define NTv  79     // ceil(V/128) logits tiles
#define TMLD 80     // tilemax row stride
#define XLD  3584   // h3x row stride: [x_hi(512) | h_hi|h_lo|h_hi(3072)]
#define XOFF 512
#define RLD  1536   // xh_r row stride: [x(512) | h(1024)]

typedef __attribute__((ext_vector_type(4))) float f32x4;
typedef __attribute__((ext_vector_type(8))) short s16x8;
typedef __attribute__((ext_vector_type(4))) short s16x4;

// Receiver gate-row permutation: orig gate-row n = g*1024+u  <->  permuted
// p = (u>>4)*64 + g*16 + (u&15).  A 128-wide MFMA tile then holds 32 complete
// (i,f,g,o) quadruples -> LSTM cell can be applied in the GEMM epilogue.
__device__ __host__ __forceinline__ int rperm_orig(int p) {
    return ((p >> 4) & 3) * Hc + (p >> 6) * 16 + (p & 15);
}

// ===========================================================================
// bf16 MFMA GEMM body (128x128 tile, BK=64, 4 waves, gld_lds w=16, swizzle)
// GemmSmem is EXACTLY 32 KiB -> 5 blocks/CU: the per-step fused dispatch
// (1144 blocks) is fully co-resident.  tile_max scratch aliases As (dead
// after the K-loop; aliased stores are behind a __syncthreads()).
// ===========================================================================
#define GBM 128
#define GBN 128
#define GBK 64

struct __align__(16) GemmSmem {
    __hip_bfloat16 As[GBM * GBK];
    __hip_bfloat16 Ws[GBN * GBK];
};

__device__ __forceinline__ void gld_lds16(void* lds, const void* g) {
    __builtin_amdgcn_global_load_lds(
        (const __attribute__((address_space(1))) unsigned int*)g,
        (__attribute__((address_space(3))) unsigned int*)lds,
        16, 0, 0);
}

template<int OBF>
__device__ __forceinline__ void gemm_body(
    GemmSmem& sm,
    const __hip_bfloat16* __restrict__ A, int lda,
    const __hip_bfloat16* __restrict__ W, int ldw,
    const float* __restrict__ bias, void* __restrict__ Cv,
    int M, int N, int K, int bx, int by,
    float* __restrict__ tile_max, int tmld)
{
    __hip_bfloat16* As = sm.As;
    __hip_bfloat16* Ws = sm.Ws;

    const int tid  = threadIdx.x;
    const int lane = tid & 63;
    const int wave = tid >> 6;
    const int m0 = by * GBM;
    const int n0 = bx * GBN;

    const __hip_bfloat16* ag[4];
    const __hip_bfloat16* wg[4];
    #pragma unroll
    for (int r = 0; r < 4; ++r) {
        int p = r * 256 + tid;
        int m = p >> 3;
        int q = (p & 7) ^ (m & 7);
        int am = m0 + m; if (am >= M) am = M - 1;
        ag[r] = A + (size_t)am * lda + q * 8;
        int wn = n0 + m; if (wn >= N) wn = N - 1;
        wg[r] = W + (size_t)wn * ldw + q * 8;
    }

    f32x4 acc[4][4];
    #pragma unroll
    for (int i = 0; i < 4; ++i)
        #pragma unroll
        for (int j = 0; j < 4; ++j)
            acc[i][j] = (f32x4)(0.0f);

    const int hm = (wave & 1) << 6;
    const int hn = (wave >> 1) << 6;
    const int lm = lane & 15;
    const int quad = lane >> 4;

    const int nk = K >> 6;
    for (int kt = 0; kt < nk; ++kt) {
        __syncthreads();
        #pragma unroll
        for (int r = 0; r < 4; ++r) {
            int ldsbase = (r * 256 + wave * 64) * 8;
            gld_lds16(As + ldsbase, ag[r]);
            gld_lds16(Ws + ldsbase, wg[r]);
            ag[r] += GBK;
            wg[r] += GBK;
        }
        __syncthreads();
        #pragma unroll
        for (int c = 0; c < 2; ++c) {
            s16x8 af[4], wf[4];
            int q = c * 4 + quad;
            #pragma unroll
            for (int i = 0; i < 4; ++i) {
                int m = hm + i * 16 + lm;
                af[i] = *(const s16x8*)(As + ((m << 3) + (q ^ (m & 7))) * 8);
                int n = hn + i * 16 + lm;
                wf[i] = *(const s16x8*)(Ws + ((n << 3) + (q ^ (n & 7))) * 8);
            }
            #pragma unroll
            for (int i = 0; i < 4; ++i)
                #pragma unroll
                for (int j = 0; j < 4; ++j)
                    acc[i][j] = __builtin_amdgcn_mfma_f32_16x16x32_bf16(
                        af[i], wf[j], acc[i][j], 0, 0, 0);
        }
    }

    // epilogue: C/D layout col=lane&15, row=quad*4+reg
    float rowmax[4][4];
    #pragma unroll
    for (int i = 0; i < 4; ++i)
        #pragma unroll
        for (int rr = 0; rr < 4; ++rr)
            rowmax[i][rr] = -__builtin_inff();

    #pragma unroll
    for (int i = 0; i < 4; ++i) {
        int mbase = m0 + hm + i * 16 + quad * 4;
        #pragma unroll
        for (int j = 0; j < 4; ++j) {
            int n = n0 + hn + j * 16 + lm;
            if (n < N) {
                float bv = bias ? bias[n] : 0.0f;
                #pragma unroll
                for (int rr = 0; rr < 4; ++rr) {
                    float v = acc[i][j][rr] + bv;
                    float vs = v;
                    if (OBF) {
                        __hip_bfloat16 vb = __float2bfloat16(v);
                        vs = __bfloat162float(vb);
                        if (mbase + rr < M)
                            ((__hip_bfloat16*)Cv)[(size_t)(mbase + rr) * N + n] = vb;
                    } else {
                        if (mbase + rr < M)
                            ((float*)Cv)[(size_t)(mbase + rr) * N + n] = v;
                    }
                    rowmax[i][rr] = fmaxf(rowmax[i][rr], vs);
                }
            }
        }
    }

    if (tile_max) {
        float* smax = (float*)sm.As;   // alias: As dead; stores are post-barrier
        #pragma unroll
        for (int i = 0; i < 4; ++i)
            #pragma unroll
            for (int rr = 0; rr < 4; ++rr) {
                float v = rowmax[i][rr];
                v = fmaxf(v, __shfl_xor(v, 1));
                v = fmaxf(v, __shfl_xor(v, 2));
                v = fmaxf(v, __shfl_xor(v, 4));
                v = fmaxf(v, __shfl_xor(v, 8));
                rowmax[i][rr] = v;
            }
        __syncthreads();
        if (hn == 0 && lm == 0) {
            #pragma unroll
            for (int i = 0; i < 4; ++i)
                #pragma unroll
                for (int rr = 0; rr < 4; ++rr)
                    smax[hm + i * 16 + quad * 4 + rr] = rowmax[i][rr];
        }
        __syncthreads();
        if (hn == 64 && lm == 0) {
            #pragma unroll
            for (int i = 0; i < 4; ++i)
                #pragma unroll
                for (int rr = 0; rr < 4; ++rr) {
                    int r = hm + i * 16 + quad * 4 + rr;
                    smax[r] = fmaxf(smax[r], rowmax[i][rr]);
                }
        }
        __syncthreads();
        if (tid < GBM)
            tile_max[(size_t)(m0 + tid) * tmld + bx] = smax[tid];
    }
}

// ---------------------------------------------------------------------------
// Receiver GEMM + fused LSTM cell (one-step-delayed recurrence).
// ---------------------------------------------------------------------------
__device__ __forceinline__ void recv_gemm_cell_body(
    GemmSmem& sm,
    const __hip_bfloat16* __restrict__ A,
    const __hip_bfloat16* __restrict__ W,
    const float* __restrict__ biasp,
    const __hip_bfloat16* __restrict__ Xg,
    const int* __restrict__ tok,
    float* __restrict__ cr,
    __hip_bfloat16* __restrict__ xh_out,
    int bx, int by)
{
    __hip_bfloat16* As = sm.As;
    __hip_bfloat16* Ws = sm.Ws;

    const int tid  = threadIdx.x;
    const int lane = tid & 63;
    const int wave = tid >> 6;
    const int m0 = by * GBM;
    const int n0 = bx * GBN;

    const __hip_bfloat16* ag[4];
    const __hip_bfloat16* wg[4];
    #pragma unroll
    for (int r = 0; r < 4; ++r) {
        int p = r * 256 + tid;
        int m = p >> 3;
        int q = (p & 7) ^ (m & 7);
        ag[r] = A + (size_t)(m0 + m) * RLD + q * 8;
        wg[r] = W + (size_t)(n0 + m) * RLD + q * 8;
    }

    f32x4 acc[4][4];
    #pragma unroll
    for (int i = 0; i < 4; ++i)
        #pragma unroll
        for (int j = 0; j < 4; ++j)
            acc[i][j] = (f32x4)(0.0f);

    const int hm = (wave & 1) << 6;
    const int hn = (wave >> 1) << 6;
    const int lm = lane & 15;
    const int quad = lane >> 4;

    for (int kt = 0; kt < Hc / GBK; ++kt) {
        __syncthreads();
        #pragma unroll
        for (int r = 0; r < 4; ++r) {
            int ldsbase = (r * 256 + wave * 64) * 8;
            gld_lds16(As + ldsbase, ag[r]);
            gld_lds16(Ws + ldsbase, wg[r]);
            ag[r] += GBK;
            wg[r] += GBK;
        }
        __syncthreads();
        #pragma unroll
        for (int c = 0; c < 2; ++c) {
            s16x8 af[4], wf[4];
            int q = c * 4 + quad;
            #pragma unroll
            for (int i = 0; i < 4; ++i) {
                int m = hm + i * 16 + lm;
                af[i] = *(const s16x8*)(As + ((m << 3) + (q ^ (m & 7))) * 8);
                int n = hn + i * 16 + lm;
                wf[i] = *(const s16x8*)(Ws + ((n << 3) + (q ^ (n & 7))) * 8);
            }
            #pragma unroll
            for (int i = 0; i < 4; ++i)
                #pragma unroll
                for (int j = 0; j < 4; ++j)
                    acc[i][j] = __builtin_amdgcn_mfma_f32_16x16x32_bf16(
                        af[i], wf[j], acc[i][j], 0, 0, 0);
        }
    }

    // epilogue: unit u = ((n0+hn)>>6)*16 + lm; gate g = j.
    const int u = ((n0 + hn) >> 6) * 16 + lm;
    int pc[4];
    float bv[4];
    #pragma unroll
    for (int g = 0; g < 4; ++g) {
        pc[g] = n0 + hn + g * 16 + lm;
        bv[g] = biasp[pc[g]];
    }
    #pragma unroll
    for (int i = 0; i < 4; ++i) {
        #pragma unroll
        for (int rr = 0; rr < 4; ++rr) {
            int b = m0 + hm + i * 16 + quad * 4 + rr;
            const __hip_bfloat16* xr = Xg + (size_t)tok[b] * G4c;
            float gi = acc[i][0][rr] + bv[0] + __bfloat162float(xr[pc[0]]);
            float gf = acc[i][1][rr] + bv[1] + __bfloat162float(xr[pc[1]]);
            float gg = acc[i][2][rr] + bv[2] + __bfloat162float(xr[pc[2]]);
            float go = acc[i][3][rr] + bv[3] + __bfloat162float(xr[pc[3]]);
            float si = 1.0f / (1.0f + expf(-gi));
            float sf = 1.0f / (1.0f + expf(-gf));
            float so = 1.0f / (1.0f + expf(-go));
            size_t cix = (size_t)b * Hc + u;
            float cc = sf * cr[cix] + si * tanhf(gg);
            cr[cix] = cc;
            xh_out[(size_t)b * RLD + Ec + u] = __float2bfloat16(so * tanhf(cc));
        }
    }
}

__global__ __launch_bounds__(256) void gemm_recv_final(
    const __hip_bfloat16* __restrict__ A, const __hip_bfloat16* __restrict__ W,
    const float* __restrict__ biasp, const __hip_bfloat16* __restrict__ Xg,
    const int* __restrict__ tok, float* __restrict__ cr,
    __hip_bfloat16* __restrict__ xh_out)
{
    __shared__ GemmSmem sm;
    recv_gemm_cell_body(sm, A, W, biasp, Xg, tok, cr, xh_out,
                        blockIdx.x & 31, blockIdx.x >> 5);
}

__global__ __launch_bounds__(256) void gemm_bf16_tn(
    const __hip_bfloat16* __restrict__ A, int lda,
    const __hip_bfloat16* __restrict__ W, int ldw,
    const float* __restrict__ bias, float* __restrict__ C,
    int M, int N, int K, float* __restrict__ tile_max, int tmld)
{
    __shared__ GemmSmem sm;
    gemm_body<0>(sm, A, lda, W, ldw, bias, C, M, N, K, blockIdx.x, blockIdx.y,
                 tile_max, tmld);
}

// bf16-output GEMM with bias (W_out projection -> r_b directly; no cast)
__global__ __launch_bounds__(256) void gemm_bf16_tn_obf(
    const __hip_bfloat16* __restrict__ A, int lda,
    const __hip_bfloat16* __restrict__ W, int ldw,
    const float* __restrict__ bias, __hip_bfloat16* __restrict__ C,
    int M, int N, int K)
{
    __shared__ GemmSmem sm;
    gemm_body<1>(sm, A, lda, W, ldw, bias, C, M, N, K, blockIdx.x, blockIdx.y,
                 nullptr, 0);
}

// split-K x2: blockIdx.z selects K-half; fp32 partials, no bias.
__global__ __launch_bounds__(256) void gemm_bf16_sk2(
    const __hip_bfloat16* __restrict__ A, int lda,
    const __hip_bfloat16* __restrict__ W, int ldw,
    float* __restrict__ Cpart, int M, int N, int Ksub)
{
    __shared__ GemmSmem sm;
    int z = blockIdx.z;
    gemm_body<0>(sm, A + (size_t)z * Ksub, lda, W + (size_t)z * Ksub, ldw,
                 nullptr, Cpart + (size_t)z * M * N, M, N, Ksub, blockIdx.x,
                 blockIdx.y, nullptr, 0);
}

// ---------------------------------------------------------------------------
// One-time table dispatch: Xg_s build (nbS blocks) || Xg_r build (nbR blocks)
// || h0 = target3 @ W_aff3^T split-K x2 (128 blocks).
// ---------------------------------------------------------------------------
__global__ __launch_bounds__(256) void gemm_tab_h0(
    int nbS, int nbR,
    const __hip_bfloat16* __restrict__ embS, const __hip_bfloat16* __restrict__ embR,
    const __hip_bfloat16* __restrict__ W3x, const __hip_bfloat16* __restrict__ Wr,
    __hip_bfloat16* __restrict__ XgS, __hip_bfloat16* __restrict__ XgR,
    const __hip_bfloat16* __restrict__ target3,
    const __hip_bfloat16* __restrict__ W_aff3, float* __restrict__ gates_p)
{
    __shared__ GemmSmem sm;
    int bid = blockIdx.x;
    if (bid < nbS) {
        gemm_body<1>(sm, embS, Ec, W3x, XLD, nullptr, XgS,
                     Vc, G4c, Ec, bid & 31, bid >> 5, nullptr, 0);
    } else if (bid < nbS + nbR) {
        int rem = bid - nbS;
        gemm_body<1>(sm, embR, Ec, Wr, RLD, nullptr, XgR,
                     Vc, G4c, Ec, rem & 31, rem >> 5, nullptr, 0);
    } else {
        int r2 = bid - nbS - nbR;     // 128 blocks: h0 sk2, Ksub=3072
        int z = r2 >> 6, rem = r2 & 63;
        gemm_body<0>(sm, target3 + (size_t)z * 3072, 6144,
                     W_aff3 + (size_t)z * 3072, 6144, nullptr,
                     gates_p + (size_t)z * Bc * Hc,
                     Bc, Hc, 3072, rem & 7, rem >> 3, nullptr, 0);
    }
}

// ---------------------------------------------------------------------------
// Fused per-step GEMM dispatch (1144 blocks max, 32KB LDS -> 5/CU, all
// co-resident):
//   blocks [0, nb_g):        sender gates(t+1) single-K (K=3072, 48 iters)
//                            -> gates_p (half 0 only)
//   blocks [nb_g, +632):     logits(t)+tilemax (16 iters; bf16 if LOGBF)
//   blocks [nb_g+632, +nb_r):recv GEMM + fused cellR(t-1) (16 iters)
// All inputs come from PREVIOUS dispatches -> no intra-dispatch deps.
// ---------------------------------------------------------------------------
template<int LOGBF>
__global__ __launch_bounds__(256) void gemm_fused_step(
    int nb_g,
    const __hip_bfloat16* __restrict__ Ag, const __hip_bfloat16* __restrict__ Wg,
    float* __restrict__ Cg,
    const __hip_bfloat16* __restrict__ Al, const __hip_bfloat16* __restrict__ Wl,
    const float* __restrict__ bl, void* __restrict__ Cl,
    float* __restrict__ tmax,
    const __hip_bfloat16* __restrict__ Ar, const __hip_bfloat16* __restrict__ Wr,
    const float* __restrict__ biasrp, const __hip_bfloat16* __restrict__ Xgr,
    const int* __restrict__ tokr, float* __restrict__ cr,
    __hip_bfloat16* __restrict__ xh_out)
{
    __shared__ GemmSmem sm;
    int bid = blockIdx.x;
    if (bid < nb_g) {
        gemm_body<0>(sm, Ag, XLD, Wg, XLD, nullptr, Cg,
                     Bc, G4c, 3072, bid & 31, bid >> 5, nullptr, 0);
    } else if (bid < nb_g + 632) {
        int rem = bid - nb_g;
        int by = rem / NTv, bx = rem - by * NTv;
        gemm_body<LOGBF>(sm, Al, XLD, Wl, Hc, bl, Cl, Bc, Vc, Hc, bx, by,
                         tmax, TMLD);
    } else {
        int rem = bid - nb_g - 632;
        recv_gemm_cell_body(sm, Ar, Wr, biasrp, Xgr, tokr, cr, xh_out,
                            rem & 31, rem >> 5);
    }
}

// ===========================================================================
// prep_all: ALL one-time elementwise prep in a single dispatch.
// ===========================================================================
#define PC0  2097152    // Wih_s cast -> W3x[:,0:512)
#define PC1  6291456    // + Whh_s split3 -> W3x[:,512:3584)
#define PC2  16531456   // + Wp cast
#define PC3  18628608   // + target split3_a -> target3 (ld 6144)
#define PC4  20725760   // + W_aff split3_w -> W_aff3 (ld 6144)
#define PC5  22822912   // + Wih_r perm cast -> WihWhh_r[:,0:512)
#define PC6  27017216   // + Whh_r perm cast -> WihWhh_r[:,512:1536)
#define PC7  29114368   // + W_out cast
#define PC8  29118464   // + bias_s add
#define PC9  29122560   // + bias_r perm add
#define PC10 34242560   // + emb_s cast
#define PC11 39362560   // + emb_r cast          (base grid)
#define PC12 41459712   // + target cast -> A4b
#define PC13 47751168   // + distr cast -> A4b+B*NIF  (extra grid)

__global__ __launch_bounds__(256) void prep_all_kernel(
    const float* __restrict__ Wih_s, const float* __restrict__ Whh_s,
    const float* __restrict__ Wp, const float* __restrict__ target,
    const float* __restrict__ W_aff, const float* __restrict__ Wih_r,
    const float* __restrict__ Whh_r, const float* __restrict__ W_out,
    const float* __restrict__ bih_s, const float* __restrict__ bhh_s,
    const float* __restrict__ bih_r, const float* __restrict__ bhh_r,
    const float* __restrict__ emb_s, const float* __restrict__ emb_r,
    const float* __restrict__ distr,
    __hip_bfloat16* __restrict__ W3x, __hip_bfloat16* __restrict__ Wp_b,
    __hip_bfloat16* __restrict__ target3, __hip_bfloat16* __restrict__ W_aff3,
    __hip_bfloat16* __restrict__ WihWhh_r, __hip_bfloat16* __restrict__ W_out_b,
    float* __restrict__ bias_s, float* __restrict__ bias_r,
    __hip_bfloat16* __restrict__ embS, __hip_bfloat16* __restrict__ embR,
    __hip_bfloat16* __restrict__ A4b)
{
    int i = blockIdx.x * 256 + threadIdx.x;
    if (i < PC0) {
        W3x[(size_t)(i / Ec) * XLD + (i % Ec)] = __float2bfloat16(Wih_s[i]);
    } else if (i < PC1) {
        int k = i - PC0; int m = k / Hc, c = k - m * Hc;
        float v = Whh_s[k];
        __hip_bfloat16 hi = __float2bfloat16(v);
        float lo = v - __bfloat162float(hi);
        __hip_bfloat16* row = W3x + (size_t)m * XLD + XOFF;
        row[c] = hi; row[Hc + c] = hi; row[2 * Hc + c] = __float2bfloat16(lo);
    } else if (i < PC2) {
        int k = i - PC1;
        Wp_b[k] = __float2bfloat16(Wp[k]);
    } else if (i < PC3) {
        int k = i - PC2; int m = k / NIFc, c = k - m * NIFc;
        float v = target[k];
        __hip_bfloat16 hi = __float2bfloat16(v);
        float lo = v - __bfloat162float(hi);
        __hip_bfloat16* row = target3 + (size_t)m * 6144;
        row[c] = hi; row[NIFc + c] = __float2bfloat16(lo); row[2 * NIFc + c] = hi;
    } else if (i < PC4) {
        int k = i - PC3; int m = k / NIFc, c = k - m * NIFc;
        float v = W_aff[k];
        __hip_bfloat16 hi = __float2bfloat16(v);
        float lo = v - __bfloat162float(hi);
        __hip_bfloat16* row = W_aff3 + (size_t)m * 6144;
        row[c] = hi; row[NIFc + c] = hi; row[2 * NIFc + c] = __float2bfloat16(lo);
    } else if (i < PC5) {
        int k = i - PC4; int p = k / Ec, c = k - p * Ec;
        WihWhh_r[(size_t)p * RLD + c] =
            __float2bfloat16(Wih_r[(size_t)rperm_orig(p) * Ec + c]);
    } else if (i < PC6) {
        int k = i - PC5; int p = k / Hc, c = k - p * Hc;
        WihWhh_r[(size_t)p * RLD + Ec + c] =
            __float2bfloat16(Whh_r[(size_t)rperm_orig(p) * Hc + c]);
    } else if (i < PC7) {
        int k = i - PC6;
        W_out_b[k] = __float2bfloat16(W_out[k]);
    } else if (i < PC8) {
        int k = i - PC7;
        bias_s[k] = bih_s[k] + bhh_s[k];
    } else if (i < PC9) {
        int k = i - PC8; int s = rperm_orig(k);
        bias_r[k] = bih_r[s] + bhh_r[s];
    } else if (i < PC10) {
        int k = i - PC9;
        embS[k] = __float2bfloat16(emb_s[k]);
    } else if (i < PC11) {
        int k = i - PC10;
        embR[k] = __float2bfloat16(emb_r[k]);
    } else if (i < PC12) {
        int k = i - PC11;
        A4b[k] = __float2bfloat16(target[k]);
    } else if (i < PC13) {
        int k = i - PC12;
        A4b[(size_t)Bc * NIFc + k] = __float2bfloat16(distr[k]);
    }
}

__global__ __launch_bounds__(256) void cast2d_kernel(
    const float* __restrict__ in, int ldin,
    __hip_bfloat16* __restrict__ out, int ldo, int coff, int M, int K)
{
    int i = blockIdx.x * 256 + threadIdx.x;
    if (i >= M * K) return;
    int m = i / K, k = i - m * K;
    out[(size_t)m * ldo + coff + k] = __float2bfloat16(in[(size_t)m * ldin + k]);
}

// gather token embedding, hi-only bf16 (fallback path)
__global__ __launch_bounds__(256) void gather_cast_kernel(
    const float* __restrict__ emb, int E, const int* __restrict__ idx,
    int stride, __hip_bfloat16* __restrict__ out, int ldo, int coff, int Brows)
{
    int i = blockIdx.x * 256 + threadIdx.x;
    if (i >= Brows * E) return;
    int b = i / E, k = i - b * E;
    out[(size_t)b * ldo + coff + k] =
        __float2bfloat16(emb[(size_t)idx[(size_t)b * stride] * E + k]);
}

// ===========================================================================
// LSTM pointwise helpers
// ===========================================================================
__device__ __forceinline__ short bf16bits(float x) {
    __hip_bfloat16 t = __float2bfloat16(x);
    return *reinterpret_cast<short*>(&t);
}

__device__ __forceinline__ float b16f(short s) {
    return __bfloat162float(*reinterpret_cast<__hip_bfloat16*>(&s));
}

// sender cell (standalone, step 0 + fallback)
__global__ __launch_bounds__(256) void lstm_fused_s(
    const float* __restrict__ gp0, const float* __restrict__ gp1,
    const float* __restrict__ bias, float* __restrict__ h,
    float* __restrict__ c, __hip_bfloat16* __restrict__ h3x,
    const __hip_bfloat16* __restrict__ xg, const int* __restrict__ tok,
    int tstride)
{
    int i = blockIdx.x * 256 + threadIdx.x;      // over Bc*Hc/4
    if (i >= Bc * Hc / 4) return;
    int b = i >> 8;
    int j = (i & 255) * 4;
    size_t g0 = (size_t)b * G4c + j;
    f32x4 gi = *(const f32x4*)(gp0 + g0) + *(const f32x4*)(gp1 + g0)
             + *(const f32x4*)(bias + j);
    f32x4 gf = *(const f32x4*)(gp0 + g0 + Hc) + *(const f32x4*)(gp1 + g0 + Hc)
             + *(const f32x4*)(bias + Hc + j);
    f32x4 gg = *(const f32x4*)(gp0 + g0 + 2 * Hc) + *(const f32x4*)(gp1 + g0 + 2 * Hc)
             + *(const f32x4*)(bias + 2 * Hc + j);
    f32x4 go = *(const f32x4*)(gp0 + g0 + 3 * Hc) + *(const f32x4*)(gp1 + g0 + 3 * Hc)
             + *(const f32x4*)(bias + 3 * Hc + j);
    if (xg) {
        const __hip_bfloat16* xr = xg + (size_t)tok[(size_t)b * tstride] * G4c;
        s16x4 xi = *(const s16x4*)(xr + j);
        s16x4 xf = *(const s16x4*)(xr + Hc + j);
        s16x4 xc = *(const s16x4*)(xr + 2 * Hc + j);
        s16x4 xo = *(const s16x4*)(xr + 3 * Hc + j);
        #pragma unroll
        for (int k = 0; k < 4; ++k) {
            gi[k] += b16f(xi[k]);
            gf[k] += b16f(xf[k]);
            gg[k] += b16f(xc[k]);
            go[k] += b16f(xo[k]);
        }
    }
    size_t hix = (size_t)b * Hc + j;
    f32x4 cv = *(const f32x4*)(c + hix);
    f32x4 cn, hv;
    s16x4 hi4, lo4;
    #pragma unroll
    for (int k = 0; k < 4; ++k) {
        float si = 1.0f / (1.0f + expf(-gi[k]));
        float sf = 1.0f / (1.0f + expf(-gf[k]));
        float so = 1.0f / (1.0f + expf(-go[k]));
        float cc = sf * cv[k] + si * tanhf(gg[k]);
        cn[k] = cc;
        float hh = so * tanhf(cc);
        hv[k] = hh;
        hi4[k] = bf16bits(hh);
        lo4[k] = bf16bits(hh - __bfloat162float(__float2bfloat16(hh)));
    }
    *(f32x4*)(c + hix) = cn;
    *(f32x4*)(h + hix) = hv;
    __hip_bfloat16* row = h3x + (size_t)b * XLD + XOFF;
    *(s16x4*)(row + j) = hi4;
    *(s16x4*)(row + Hc + j) = lo4;
    *(s16x4*)(row + 2 * Hc + j) = hi4;
}

__global__ __launch_bounds__(256) void combine_h0_kernel(
    const float* __restrict__ p0, const float* __restrict__ p1,
    const float* __restrict__ bias, float* __restrict__ h,
    __hip_bfloat16* __restrict__ h3x)
{
    int i = blockIdx.x * 256 + threadIdx.x;
    if (i >= Bc * Hc / 4) return;
    int b = i >> 8;
    int j = (i & 255) * 4;
    size_t ix = (size_t)b * Hc + j;
    f32x4 v = *(const f32x4*)(p0 + ix) + *(const f32x4*)(p1 + ix)
            + *(const f32x4*)(bias + j);
    *(f32x4*)(h + ix) = v;
    s16x4 hi4, lo4;
    #pragma unroll
    for (int k = 0; k < 4; ++k) {
        hi4[k] = bf16bits(v[k]);
        lo4[k] = bf16bits(v[k] - __bfloat162float(__float2bfloat16(v[k])));
    }
    __hip_bfloat16* row = h3x + (size_t)b * XLD + XOFF;
    *(s16x4*)(row + j) = hi4;
    *(s16x4*)(row + Hc + j) = lo4;
    *(s16x4*)(row + 2 * Hc + j) = hi4;
}

// receiver cell (fallback path only) — gates/bias/Xg in PERMUTED column order
__global__ __launch_bounds__(256) void lstm_fused_r(
    const float* __restrict__ gp0, const float* __restrict__ gp1,
    const float* __restrict__ bias, float* __restrict__ h,
    float* __restrict__ c, __hip_bfloat16* __restrict__ xh_r,
    const __hip_bfloat16* __restrict__ xg, const int* __restrict__ tok,
    int has_g, const float* __restrict__ emb, const int* __restrict__ msg_next)
{
    int i = blockIdx.x * 256 + threadIdx.x;
    if (i >= Bc * Hc / 4) return;
    int b = i >> 8;
    int j = (i & 255) * 4;                 // unit base, 4 consecutive units
    int pb = (j >> 4) * 64 + (j & 15);     // permuted col base (gate 0)
    f32x4 gi = *(const f32x4*)(bias + pb);
    f32x4 gf = *(const f32x4*)(bias + pb + 16);
    f32x4 gg = *(const f32x4*)(bias + pb + 32);
    f32x4 go = *(const f32x4*)(bias + pb + 48);
    if (has_g) {
        size_t g0 = (size_t)b * G4c + pb;
        gi += *(const f32x4*)(gp0 + g0) + *(const f32x4*)(gp1 + g0);
        gf += *(const f32x4*)(gp0 + g0 + 16) + *(const f32x4*)(gp1 + g0 + 16);
        gg += *(const f32x4*)(gp0 + g0 + 32) + *(const f32x4*)(gp1 + g0 + 32);
        go += *(const f32x4*)(gp0 + g0 + 48) + *(const f32x4*)(gp1 + g0 + 48);
    }
    if (xg) {
        const __hip_bfloat16* xr = xg + (size_t)tok[b] * G4c;
        s16x4 xi = *(const s16x4*)(xr + pb);
        s16x4 xf = *(const s16x4*)(xr + pb + 16);
        s16x4 xc = *(const s16x4*)(xr + pb + 32);
        s16x4 xo = *(const s16x4*)(xr + pb + 48);
        #pragma unroll
        for (int k = 0; k < 4; ++k) {
            gi[k] += b16f(xi[k]);
            gf[k] += b16f(xf[k]);
            gg[k] += b16f(xc[k]);
            go[k] += b16f(xo[k]);
        }
    }
    size_t hix = (size_t)b * Hc + j;
    f32x4 cv = *(const f32x4*)(c + hix);
    f32x4 cn, hv;
    s16x4 hb4;
    #pragma unroll
    for (int k = 0; k < 4; ++k) {
        float si = 1.0f / (1.0f + expf(-gi[k]));
        float sf = 1.0f / (1.0f + expf(-gf[k]));
        float so = 1.0f / (1.0f + expf(-go[k]));
        float cc = sf * cv[k] + si * tanhf(gg[k]);
        cn[k] = cc;
        float hh = so * tanhf(cc);
        hv[k] = hh;
        hb4[k] = bf16bits(hh);
    }
    *(f32x4*)(c + hix) = cn;
    *(f32x4*)(h + hix) = hv;
    *(s16x4*)(xh_r + (size_t)b * RLD + Ec + j) = hb4;
    if (!xg && msg_next && j < Ec) {
        int t2 = msg_next[b];
        f32x4 e = *(const f32x4*)(emb + (size_t)t2 * Ec + j);
        s16x4 eb;
        #pragma unroll
        for (int k = 0; k < 4; ++k) eb[k] = bf16bits(e[k]);
        *(s16x4*)(xh_r + (size_t)b * RLD + j) = eb;
    }
}

// ===========================================================================
// argmax v3 (fallback standalone version, fp32 logits)
// ===========================================================================
__global__ __launch_bounds__(256) void argmax_rescore_v3(
    const float* __restrict__ logits, const float* __restrict__ tmax,
    const float* __restrict__ h, const float* __restrict__ Wp,
    const float* __restrict__ bp, const float* __restrict__ emb,
    int* __restrict__ msg_t, float* __restrict__ logp,
    __hip_bfloat16* __restrict__ xdst, int want_logp)
{
    const int b = blockIdx.x;
    const int tid = threadIdx.x;
    const int lane = tid & 63;
    const int wave = tid >> 6;
    const float* row = logits + (size_t)b * Vc;

    __shared__ float stm[128];
    __shared__ float redm[256];
    __shared__ float reds[256];
    __shared__ int   qt[32];
    __shared__ int   nq, cnt;
    __shared__ int   cand[64];
    __shared__ float score[64];
    __shared__ float sbestv;
    __shared__ int   sbestj;

    float tv = (tid < NTv) ? tmax[(size_t)b * TMLD + tid] : -__builtin_inff();
    if (tid < 128) stm[tid] = tv;
    redm[tid] = tv;
    reds[tid] = (tid < NTv) ? tv : 0.0f;
    if (tid == 0) { nq = 0; cnt = 0; }
    __syncthreads();
    #pragma unroll
    for (int s = 128; s > 0; s >>= 1) {
        if (tid < s) {
            redm[tid] = fmaxf(redm[tid], redm[tid + s]);
            reds[tid] += reds[tid + s];
        }
        __syncthreads();
    }
    const float m = redm[0];
    const float spread = m - reds[0] * (1.0f / NTv);
    const float delta = 0.08f * spread + 1e-6f * (1.0f + fabsf(m));

    if (tid < NTv && stm[tid] >= m - delta) {
        int k = atomicAdd(&nq, 1);
        if (k < 32) qt[k] = tid;
    }
    __syncthreads();
    int nqt = nq < 32 ? nq : 32;

    for (int qi = 0; qi < nqt; qi += 2) {
        int ti = qi + (tid >> 7);
        if (ti < nqt) {
            int j = qt[ti] * 128 + (tid & 127);
            if (j < Vc) {
                float v = row[j];
                if (v >= m - delta) {
                    int k = atomicAdd(&cnt, 1);
                    if (k < 64) cand[k] = j;
                }
            }
        }
    }
    __syncthreads();
    int nc = cnt < 64 ? cnt : 64;

    const float* hrow = h + (size_t)b * Hc;
    for (int cix = wave; cix < nc; cix += 4) {
        int j = cand[cix];
        const float* wrow = Wp + (size_t)j * Hc;
        float part = 0.0f;
        #pragma unroll
        for (int kk = 0; kk < 4; ++kk) {
            int k = kk * 256 + lane * 4;
            f32x4 hv = *(const f32x4*)(hrow + k);
            f32x4 wv = *(const f32x4*)(wrow + k);
            part = fmaf(hv.x, wv.x, part);
            part = fmaf(hv.y, wv.y, part);
            part = fmaf(hv.z, wv.z, part);
            part = fmaf(hv.w, wv.w, part);
        }
        #pragma unroll
        for (int off = 1; off < 64; off <<= 1)
            part += __shfl_xor(part, off);
        if (lane == 0) score[cix] = part + bp[j];
    }
    __syncthreads();
    if (tid == 0) {
        float bv = -__builtin_inff();
        int bj = 0x7fffffff;
        for (int cix = 0; cix < nc; ++cix) {
            float v = score[cix];
            int j = cand[cix];
            if (v > bv || (v == bv && j < bj)) { bv = v; bj = j; }
        }
        sbestv = bv;
        sbestj = bj;
        msg_t[b] = bj;
    }
    __syncthreads();
    const int bestj = sbestj;

    if (want_logp) {
        float s = 0.0f;
        const f32x4* row4 = (const f32x4*)row;
        for (int j = tid; j < Vc / 4; j += 256) {
            f32x4 v = row4[j];
            s += expf(v.x - m) + expf(v.y - m) + expf(v.z - m) + expf(v.w - m);
        }
        redm[tid] = s;
        __syncthreads();
        #pragma unroll
        for (int st = 128; st > 0; st >>= 1) {
            if (tid < st) redm[tid] += redm[tid + st];
            __syncthreads();
        }
        if (tid == 0) logp[b] = sbestv - (m + logf(redm[0]));
    }

    if (xdst && tid < 128) {
        int k = tid * 4;
        f32x4 e = *(const f32x4*)(emb + (size_t)bestj * Ec + k);
        s16x4 h4;
        #pragma unroll
        for (int kk = 0; kk < 4; ++kk) h4[kk] = bf16bits(e[kk]);
        *(s16x4*)(xdst + (size_t)b * XLD + k) = h4;
    }
}

// ===========================================================================
// Per-step argmax(t) + sender cell(t+1).  1024 blocks, ~3.5 KB LDS -> fully
// resident.  Sender gates are a SINGLE fp32 partial (gp0, K=3072).
// ===========================================================================
template<int LGBF>
__global__ __launch_bounds__(256) void argmax_cell(
    const void* __restrict__ logits_v, const float* __restrict__ tmax,
    const float* __restrict__ h, const float* __restrict__ Wp,
    const float* __restrict__ bp, int* __restrict__ msg_t,
    float* __restrict__ logp, int want_logp,
    int do_s, const float* __restrict__ gp0,
    const float* __restrict__ bias_s, float* __restrict__ h_s,
    float* __restrict__ c_s, __hip_bfloat16* __restrict__ h3x,
    const __hip_bfloat16* __restrict__ Xg_s)
{
    const int b = blockIdx.x;
    const int tid = threadIdx.x;
    const int lane = tid & 63;
    const int wave = tid >> 6;
    const __hip_bfloat16* rowb = (const __hip_bfloat16*)logits_v + (size_t)b * Vc;
    const float* rowf = (const float*)logits_v + (size_t)b * Vc;

    __shared__ float stm[128];
    __shared__ float redm[256];
    __shared__ float reds[256];
    __shared__ int   qt[32];
    __shared__ int   cand[64];
    __shared__ float score[64];
    __shared__ int   nq, cnt, sbestj;
    __shared__ float sbestv;

    // ---------------- phase A: argmax ----------------
    float tv = (tid < NTv) ? tmax[(size_t)b * TMLD + tid] : -__builtin_inff();
    if (tid < 128) stm[tid] = tv;
    redm[tid] = tv;
    reds[tid] = (tid < NTv) ? tv : 0.0f;
    if (tid == 0) { nq = 0; cnt = 0; }
    __syncthreads();
    #pragma unroll
    for (int s = 128; s > 0; s >>= 1) {
        if (tid < s) {
            redm[tid] = fmaxf(redm[tid], redm[tid + s]);
            reds[tid] += reds[tid + s];
        }
        __syncthreads();
    }
    const float m = redm[0];
    const float spread = m - reds[0] * (1.0f / NTv);
    const float delta = 0.08f * spread + 1e-6f * (1.0f + fabsf(m));

    if (tid < NTv && stm[tid] >= m - delta) {
        int k = atomicAdd(&nq, 1);
        if (k < 32) qt[k] = tid;
    }
    __syncthreads();
    int nqt = nq < 32 ? nq : 32;

    for (int qi = 0; qi < nqt; qi += 2) {
        int ti = qi + (tid >> 7);
        if (ti < nqt) {
            int j = qt[ti] * 128 + (tid & 127);
            if (j < Vc) {
                float v = LGBF ? __bfloat162float(rowb[j]) : rowf[j];
                if (v >= m - delta) {
                    int k = atomicAdd(&cnt, 1);
                    if (k < 64) cand[k] = j;
                }
            }
        }
    }
    __syncthreads();
    int nc = cnt < 64 ? cnt : 64;   // >=1: stored max qualifies by construction

    const float* hrow = h + (size_t)b * Hc;
    for (int cix = wave; cix < nc; cix += 4) {
        int j = cand[cix];
        const float* wrow = Wp + (size_t)j * Hc;
        float part = 0.0f;
        #pragma unroll
        for (int kk = 0; kk < 4; ++kk) {
            int k = kk * 256 + lane * 4;
            f32x4 hv = *(const f32x4*)(hrow + k);
            f32x4 wv = *(const f32x4*)(wrow + k);
            part = fmaf(hv.x, wv.x, part);
            part = fmaf(hv.y, wv.y, part);
            part = fmaf(hv.z, wv.z, part);
            part = fmaf(hv.w, wv.w, part);
        }
        #pragma unroll
        for (int off = 1; off < 64; off <<= 1)
            part += __shfl_xor(part, off);
        if (lane == 0) score[cix] = part + bp[j];
    }
    __syncthreads();
    if (tid == 0) {
        float bv = -__builtin_inff();
        int bj = 0x7fffffff;
        for (int cix = 0; cix < nc; ++cix) {
            float v = score[cix];
            int j = cand[cix];
            if (v > bv || (v == bv && j < bj)) { bv = v; bj = j; }
        }
        sbestv = bv;
        sbestj = bj;
        msg_t[b] = bj;
    }
    __syncthreads();
    const int tok = sbestj;

    if (!LGBF && want_logp) {
        float s = 0.0f;
        const f32x4* row4 = (const f32x4*)rowf;
        for (int j = tid; j < Vc / 4; j += 256) {
            f32x4 v = row4[j];
            s += expf(v.x - m) + expf(v.y - m) + expf(v.z - m) + expf(v.w - m);
        }
        redm[tid] = s;
        __syncthreads();
        #pragma unroll
        for (int st = 128; st > 0; st >>= 1) {
            if (tid < st) redm[tid] += redm[tid + st];
            __syncthreads();
        }
        if (tid == 0) logp[b] = sbestv - (m + logf(redm[0]));
        __syncthreads();
    }

    // ---------------- phase B: sender lstm (t+1), row b ----------------
    if (do_s) {
        const int j = tid * 4;
        size_t g0 = (size_t)b * G4c + j;
        f32x4 gi = *(const f32x4*)(gp0 + g0) + *(const f32x4*)(bias_s + j);
        f32x4 gf = *(const f32x4*)(gp0 + g0 + Hc) + *(const f32x4*)(bias_s + Hc + j);
        f32x4 gg = *(const f32x4*)(gp0 + g0 + 2 * Hc) + *(const f32x4*)(bias_s + 2 * Hc + j);
        f32x4 go = *(const f32x4*)(gp0 + g0 + 3 * Hc) + *(const f32x4*)(bias_s + 3 * Hc + j);
        const __hip_bfloat16* xr = Xg_s + (size_t)tok * G4c;
        s16x4 xi = *(const s16x4*)(xr + j);
        s16x4 xf = *(const s16x4*)(xr + Hc + j);
        s16x4 xc = *(const s16x4*)(xr + 2 * Hc + j);
        s16x4 xo = *(const s16x4*)(xr + 3 * Hc + j);
        size_t hix = (size_t)b * Hc + j;
        f32x4 cv = *(const f32x4*)(c_s + hix);
        f32x4 cn, hv;
        s16x4 hi4, lo4;
        #pragma unroll
        for (int k = 0; k < 4; ++k) {
            float gik = gi[k] + b16f(xi[k]);
            float gfk = gf[k] + b16f(xf[k]);
            float ggk = gg[k] + b16f(xc[k]);
            float gok = go[k] + b16f(xo[k]);
            float si = 1.0f / (1.0f + expf(-gik));
            float sf = 1.0f / (1.0f + expf(-gfk));
            float so = 1.0f / (1.0f + expf(-gok));
            float cc = sf * cv[k] + si * tanhf(ggk);
            cn[k] = cc;
            float hh = so * tanhf(cc);
            hv[k] = hh;
            hi4[k] = bf16bits(hh);
            lo4[k] = bf16bits(hh - __bfloat162float(__float2bfloat16(hh)));
        }
        *(f32x4*)(c_s + hix) = cn;
        *(f32x4*)(h_s + hix) = hv;
        __hip_bfloat16* orow = h3x + (size_t)b * XLD + XOFF;
        *(s16x4*)(orow + j) = hi4;
        *(s16x4*)(orow + Hc + j) = lo4;
        *(s16x4*)(orow + 2 * Hc + j) = hi4;
    }
}

// ===========================================================================
// Hinge loss partial reduction; S layout [4][B][B]
// ===========================================================================
__global__ __launch_bounds__(256) void hinge_kernel(
    const float* __restrict__ S, const float* __restrict__ logp,
    float* __restrict__ partials, int Bn)
{
    int tid = threadIdx.x;
    int n = Bn * Bn;
    float acc = 0.0f;
    for (int idx = blockIdx.x * 256 + tid; idx < n; idx += gridDim.x * 256) {
        int j = idx & (Bn - 1);
        float s0 = S[idx];
        float l = fmaxf(0.0f, 1.0f - s0 + S[n + idx])
                + fmaxf(0.0f, 1.0f - s0 + S[2 * n + idx])
                + fmaxf(0.0f, 1.0f - s0 + S[3 * n + idx]);
        acc += l * logp[j];
    }
    __shared__ float sv[256];
    sv[tid] = acc;
    __syncthreads();
    for (int s = 128; s > 0; s >>= 1) {
        if (tid < s) sv[tid] += sv[tid + s];
        __syncthreads();
    }
    if (tid == 0) partials[blockIdx.x] = sv[0];
}

__global__ __launch_bounds__(256) void final_reduce_kernel(
    const float* __restrict__ partials, int np, float* __restrict__ out,
    float scale)
{
    int tid = threadIdx.x;
    float acc = 0.0f;
    for (int i = tid; i < np; i += 256) acc += partials[i];
    __shared__ float sv[256];
    sv[tid] = acc;
    __syncthreads();
    for (int s = 128; s > 0; s >>= 1) {
        if (tid < s) sv[tid] += sv[tid + s];
        __syncthreads();
    }
    if (tid == 0) out[0] = sv[0] * scale;
}

// ===========================================================================
extern "C" void kernel_launch(void* const* d_in, const int* in_sizes, int n_in,
                              void* d_out, int out_size, void* d_ws, size_t ws_size,
                              hipStream_t stream)
{
    (void)in_sizes; (void)n_in; (void)out_size;

    const float* target  = (const float*)d_in[0];
    const float* distr   = (const float*)d_in[1];
    const int*   start_t = (const int*)d_in[2];
    const float* W_aff = (const float*)d_in[4];
    const float* b_aff = (const float*)d_in[5];
    const float* emb_s = (const float*)d_in[6];
    const float* Wih_s = (const float*)d_in[7];
    const float* Whh_s = (const float*)d_in[8];
    const float* bih_s = (const float*)d_in[9];
    const float* bhh_s = (const float*)d_in[10];
    const float* Wp    = (const float*)d_in[11];
    const float* bp    = (const float*)d_in[12];
    const float* emb_r = (const float*)d_in[13];
    const float* Wih_r = (const float*)d_in[14];
    const float* Whh_r = (const float*)d_in[15];
    const float* bih_r = (const float*)d_in[16];
    const float* bhh_r = (const float*)d_in[17];
    const float* W_out = (const float*)d_in[18];
    const float* b_out = (const float*)d_in[19];

    dim3 blk(256);

    // ---------------- workspace layout ----------------
    char* b0 = (char*)d_ws;
    size_t off = 0;
    auto take = [&](size_t bytes) -> char* {
        char* p = b0 + off;
        off += (bytes + 511) & ~(size_t)511;
        return p;
    };
    const size_t MB = 1024 * 1024;
    __hip_bfloat16* W3x     = (__hip_bfloat16*)take((size_t)G4c * XLD * 2);
    __hip_bfloat16* Wp_b    = (__hip_bfloat16*)take((size_t)Vc * Hc * 2);
    __hip_bfloat16* WihWhh_r= (__hip_bfloat16*)take((size_t)G4c * RLD * 2); // PERM rows
    __hip_bfloat16* W_out_b = (__hip_bfloat16*)take((size_t)NIFc * Hc * 2);
    __hip_bfloat16* h3x     = (__hip_bfloat16*)take((size_t)Bc * XLD * 2);
    __hip_bfloat16* xh_rA   = (__hip_bfloat16*)take((size_t)Bc * RLD * 2);
    __hip_bfloat16* xh_rB   = (__hip_bfloat16*)take((size_t)Bc * RLD * 2);
    float* gates_p = (float*)take((size_t)2 * Bc * G4c * 4);
    float* h_s    = (float*)take((size_t)Bc * Hc * 4);
    float* c_s    = (float*)take((size_t)Bc * Hc * 4);
    float* hr     = (float*)take((size_t)Bc * Hc * 4);
    float* cr     = (float*)take((size_t)Bc * Hc * 4);
    float* logp   = (float*)take(Bc * 4);
    int*   msg    = (int*)take((size_t)Lc * Bc * 4);
    float* parts  = (float*)take(1024 * 4);
    float* bias_s = (float*)take(G4c * 4);
    float* bias_r = (float*)take(G4c * 4);   // PERMUTED content
    float* tilemax= (float*)take((size_t)Bc * TMLD * 4);
    char*  U      = take(48 * MB);

    // Optional precomputed x-gate tables (gated on ws_size).
    __hip_bfloat16* Xg_s = (__hip_bfloat16*)take((size_t)Vc * G4c * 2);
    const int use_tab_s = (off <= ws_size);
    __hip_bfloat16* Xg_r = (__hip_bfloat16*)take((size_t)Vc * G4c * 2); // PERM cols
    const int use_tab_r = (off <= ws_size);
    const int use_merged = use_tab_s && use_tab_r;
    // Optional dedicated sim-GEMM buffers -> A4b/distr casts fold into prep_all
    __hip_bfloat16* A4b_ws = (__hip_bfloat16*)take((size_t)4 * Bc * NIFc * 2);
    __hip_bfloat16* r_b_ws = (__hip_bfloat16*)take((size_t)Bc * NIFc * 2);
    const int use_extra = (off <= ws_size);

    // U sub-layout (phased reuse)
    __hip_bfloat16* target3 = (__hip_bfloat16*)U;                 // phase 1
    __hip_bfloat16* W_aff3  = (__hip_bfloat16*)(U + 13 * MB);     // phase 1
    __hip_bfloat16* emb_bS  = (__hip_bfloat16*)(U + 26 * MB);     // phase 1
    __hip_bfloat16* emb_bR  = (__hip_bfloat16*)(U + 36 * MB);     // phase 1
    float*          logits  = (float*)U;                          // phase 2
    __hip_bfloat16* A4b_u   = (__hip_bfloat16*)U;                 // phase 3 (fallback)
    __hip_bfloat16* r_b_u   = (__hip_bfloat16*)(U + 26 * MB);     // phase 3 (fallback)
    float*          S       = (float*)(U + 31 * MB);              // phase 3

    __hip_bfloat16* A4b = use_extra ? A4b_ws : A4b_u;
    __hip_bfloat16* r_b = use_extra ? r_b_ws : r_b_u;

    // ---- ALL one-time elementwise prep in ONE dispatch ----
    const int base_blocks  = (PC11 + 255) / 256;
    const int extra_blocks = (PC13 + 255) / 256;
    prep_all_kernel<<<use_extra ? extra_blocks : base_blocks, blk, 0, stream>>>(
        Wih_s, Whh_s, Wp, target, W_aff, Wih_r, Whh_r, W_out,
        bih_s, bhh_s, bih_r, bhh_r, emb_s, emb_r, distr,
        W3x, Wp_b, target3, W_aff3, WihWhh_r, W_out_b, bias_s, bias_r,
        emb_bS, emb_bR, A4b);

    // ---- Xg_s || Xg_r || h0 GEMMs in ONE dispatch ----
    const int nbS = use_tab_s ? 2528 : 0;
    const int nbR = use_tab_r ? 2528 : 0;
    gemm_tab_h0<<<nbS + nbR + 128, blk, 0, stream>>>(
        nbS, nbR, emb_bS, emb_bR, W3x, WihWhh_r, Xg_s, Xg_r,
        target3, W_aff3, gates_p);

    combine_h0_kernel<<<(Bc * Hc / 4 + 255) / 256, blk, 0, stream>>>(
        gates_p, gates_p + (size_t)Bc * Hc, b_aff, h_s, h3x);
    hipMemsetAsync(c_s, 0, (size_t)Bc * Hc * 4, stream);

    if (use_merged) {
        // ================= merged sender+receiver pipeline =================
        hipMemsetAsync(cr, 0, (size_t)Bc * Hc * 4, stream);
        hipMemsetAsync(xh_rA, 0, (size_t)Bc * RLD * 2, stream);   // R_0 = 0

        // step 0: gates(0) (sk2) + lstm_s(0) with start token
        gemm_bf16_sk2<<<dim3(G4c / GBN, Bc / GBM, 2), blk, 0, stream>>>(
            h3x + XOFF, XLD, W3x + XOFF, XLD, gates_p, Bc, G4c, 1536);
        lstm_fused_s<<<(Bc * Hc / 4 + 255) / 256, blk, 0, stream>>>(
            gates_p, gates_p + (size_t)Bc * G4c, bias_s, h_s, c_s, h3x,
            Xg_s, start_t, 0);

        for (int t = 0; t < Lc; ++t) {
            const int nb_g = (t < Lc - 1) ? 256 : 0;   // single-K gates(t+1)
            const int nb_r = (t >= 1) ? 256 : 0;       // recv cellR(t-1)
            const int k = t - 1;
            const __hip_bfloat16* rin = (k & 1) ? xh_rB : xh_rA;
            __hip_bfloat16* rout = (k & 1) ? xh_rA : xh_rB;
            const int* tokr = (t >= 1) ? (msg + (t - 1) * Bc) : msg;
            if (t < Lc - 1) {
                gemm_fused_step<1><<<nb_g + 632 + nb_r, blk, 0, stream>>>(
                    nb_g,
                    h3x + XOFF, W3x + XOFF, gates_p,
                    h3x + XOFF, Wp_b, bp, (void*)logits, tilemax,
                    rin + Ec, WihWhh_r + Ec, bias_r, Xg_r, tokr, cr, rout);
                argmax_cell<1><<<Bc, blk, 0, stream>>>(
                    (const void*)logits, tilemax, h_s, Wp, bp, msg + t * Bc,
                    logp, 0, 1, gates_p, bias_s, h_s, c_s, h3x, Xg_s);
            } else {
                gemm_fused_step<0><<<632 + nb_r, blk, 0, stream>>>(
                    0,
                    h3x + XOFF, W3x + XOFF, gates_p,
                    h3x + XOFF, Wp_b, bp, (void*)logits, tilemax,
                    rin + Ec, WihWhh_r + Ec, bias_r, Xg_r, tokr, cr, rout);
                argmax_cell<0><<<Bc, blk, 0, stream>>>(
                    (const void*)logits, tilemax, h_s, Wp, bp, msg + t * Bc,
                    logp, 1, 0, gates_p, bias_s, h_s, c_s, h3x, Xg_s);
            }
        }
        // final receiver app k=31: reads xh_rB (R_31), writes xh_rA (R_32)
        gemm_recv_final<<<256, blk, 0, stream>>>(
            xh_rB + Ec, WihWhh_r + Ec, bias_r, Xg_r, msg + (Lc - 1) * Bc,
            cr, xh_rA);
    } else {
        // ================= fallback: serial structure =================
        if (!use_tab_s)
            gather_cast_kernel<<<(Bc * Ec + 255) / 256, blk, 0, stream>>>(
                emb_s, Ec, start_t, 0, h3x, XLD, 0, Bc);

        for (int t = 0; t < Lc; ++t) {
            if (use_tab_s) {
                gemm_bf16_sk2<<<dim3(G4c / GBN, Bc / GBM, 2), blk, 0, stream>>>(
                    h3x + XOFF, XLD, W3x + XOFF, XLD, gates_p, Bc, G4c, 1536);
                lstm_fused_s<<<(Bc * Hc / 4 + 255) / 256, blk, 0, stream>>>(
                    gates_p, gates_p + (size_t)Bc * G4c, bias_s, h_s, c_s, h3x,
                    Xg_s, (t == 0) ? start_t : (msg + (t - 1) * Bc),
                    (t == 0) ? 0 : 1);
            } else {
                gemm_bf16_sk2<<<dim3(G4c / GBN, Bc / GBM, 2), blk, 0, stream>>>(
                    h3x, XLD, W3x, XLD, gates_p, Bc, G4c, 1792);
                lstm_fused_s<<<(Bc * Hc / 4 + 255) / 256, blk, 0, stream>>>(
                    gates_p, gates_p + (size_t)Bc * G4c, bias_s, h_s, c_s, h3x,
                    nullptr, nullptr, 0);
            }
            gemm_bf16_tn<<<dim3((Vc + GBN - 1) / GBN, Bc / GBM), blk, 0, stream>>>(
                h3x + XOFF, XLD, Wp_b, Hc, bp, logits, Bc, Vc, Hc, tilemax, TMLD);
            argmax_rescore_v3<<<Bc, blk, 0, stream>>>(
                logits, tilemax, h_s, Wp, bp, emb_s, msg + t * Bc, logp,
                (!use_tab_s && t < Lc - 1) ? h3x : nullptr,
                (t == Lc - 1) ? 1 : 0);
        }

        hipMemsetAsync(hr, 0, (size_t)Bc * Hc * 4, stream);
        hipMemsetAsync(cr, 0, (size_t)Bc * Hc * 4, stream);
        hipMemsetAsync(xh_rA, 0, (size_t)Bc * RLD * 2, stream);
        if (!use_tab_r)
            gather_cast_kernel<<<(Bc * Ec + 255) / 256, blk, 0, stream>>>(
                emb_r, Ec, msg, 1, xh_rA, RLD, 0, Bc);
        for (int t = 0; t < Lc; ++t) {
            if (use_tab_r) {
                if (t > 0)
                    gemm_bf16_sk2<<<dim3(G4c / GBN, Bc / GBM, 2), blk, 0, stream>>>(
                        xh_rA + Ec, RLD, WihWhh_r + Ec, RLD, gates_p, Bc, G4c, 512);
                lstm_fused_r<<<(Bc * Hc / 4 + 255) / 256, blk, 0, stream>>>(
                    gates_p, gates_p + (size_t)Bc * G4c, bias_r, hr, cr, xh_rA,
                    Xg_r, msg + t * Bc, (t > 0) ? 1 : 0, nullptr, nullptr);
            } else {
                gemm_bf16_sk2<<<dim3(G4c / GBN, Bc / GBM, 2), blk, 0, stream>>>(
                    xh_rA, RLD, WihWhh_r, RLD, gates_p, Bc, G4c, 768);
                lstm_fused_r<<<(Bc * Hc / 4 + 255) / 256, blk, 0, stream>>>(
                    gates_p, gates_p + (size_t)Bc * G4c, bias_r, hr, cr, xh_rA,
                    nullptr, nullptr, 1, emb_r,
                    (t < Lc - 1) ? (msg + (t + 1) * Bc) : nullptr);
            }
        }
    }

    // ---- r = hR_final @ W_out^T + b_out, bf16 out directly ----
    gemm_bf16_tn_obf<<<dim3(NIFc / GBN, Bc / GBM), blk, 0, stream>>>(
        xh_rA + Ec, RLD, W_out_b, Hc, b_out, r_b, Bc, NIFc, Hc);

    // ---- similarities: [target; distractors] @ r^T in ONE GEMM ----
    if (!use_extra) {
        cast2d_kernel<<<(Bc * NIFc + 255) / 256, blk, 0, stream>>>(
            target, NIFc, A4b, NIFc, 0, Bc, NIFc);
        cast2d_kernel<<<(NDc * Bc * NIFc + 255) / 256, blk, 0, stream>>>(
            distr, NIFc, A4b + (size_t)Bc * NIFc, NIFc, 0, NDc * Bc, NIFc);
    }
    gemm_bf16_tn<<<dim3(Bc / GBN, 4 * Bc / GBM), blk, 0, stream>>>(
        A4b, NIFc, r_b, NIFc, nullptr, S, 4 * Bc, Bc, NIFc, nullptr, 0);

    hinge_kernel<<<1024, blk, 0, stream>>>(S, logp, parts, Bc);
    final_reduce_kernel<<<1, blk, 0, stream>>>(
        parts, 1024, (float*)d_out, -1.0f / ((float)Bc * (float)Bc));
}